// Round 3
// baseline (1515.424 us; speedup 1.0000x reference)
//
#include <hip/hip_runtime.h>

// TopK-SAE forward, MI355X. Strategy:
//  - normalize rows (f32) + bf16 copy
//  - bf16 MFMA GEMM (128x128 tile, global_load_lds w16) -> approx acts (bf16,
//    staged in the acts_topk output region which is rewritten later)
//  - per-row histogram select: top-48 enc candidates (margin over 32),
//    exact top-256 (by approx) of dead features for aux
//  - exact f64 recompute of the 48 candidates from f32 xn / W_enc^T -> exact top-32
//  - sparse decode (32 gathers), aux decode (256 gathers, bf16 W_dec),
//    cosine penalty (32x32 pair dots, bf16 LDS stage), scalar losses via f64 atomics
// WS footprint ~96.3MB; f32 W_enc^T (75.5MB) staged in the unused upper half of
// the d_out acts region (valid: read by k_recompute before k_zero overwrites).

typedef unsigned int u32;
typedef unsigned short u16;
typedef unsigned long long u64;
using short8 = __attribute__((ext_vector_type(8))) short;
using f32x4  = __attribute__((ext_vector_type(4))) float;

#define NB    2048
#define DIM   768
#define DICT  24576
#define TK    32
#define TKA   256
#define KENC  48

__device__ __forceinline__ u16 f2bf(float f) {
    u32 u = __float_as_uint(f);
    u32 r = (u + 0x7FFFu + ((u >> 16) & 1u)) >> 16;
    return (u16)r;
}
__device__ __forceinline__ float bf2f(u16 b) { return __uint_as_float(((u32)b) << 16); }

__device__ __forceinline__ float waveSum(float v) {
    #pragma unroll
    for (int o = 32; o; o >>= 1) v += __shfl_xor(v, o);
    return v;
}
__device__ __forceinline__ float blockSum(float v, float* red) {
    __syncthreads();
    v = waveSum(v);
    if ((threadIdx.x & 63) == 0) red[threadIdx.x >> 6] = v;
    __syncthreads();
    return red[0] + red[1] + red[2] + red[3];
}

// ---------------------------------------------------------------- init
__global__ __launch_bounds__(256) void k_init(double* acc8, u32* deadw,
                                              const int* __restrict__ nba, float* eb) {
    int t = blockIdx.x * 256 + threadIdx.x;
    if (t < 8) acc8[t] = 0.0;
    if (t < DICT / 32) {
        u32 w = 0;
        const int* p = nba + t * 32;
        #pragma unroll
        for (int b = 0; b < 32; b++) if (p[b] >= 5) w |= (1u << b);
        deadw[t] = w;
    }
    if (t < DICT) eb[t] = 0.f;
}

// ---------------------------------------------------------------- normalize
__global__ __launch_bounds__(256) void k_norm(const float* __restrict__ x,
                                              float* __restrict__ xn, u16* __restrict__ xnb,
                                              float* __restrict__ mean, float* __restrict__ sd) {
    __shared__ float red[4];
    int r = blockIdx.x, t = threadIdx.x;
    const float* xr = x + (size_t)r * DIM;
    float v0 = xr[t], v1 = xr[t + 256], v2 = xr[t + 512];
    float s = blockSum(v0 + v1 + v2, red);
    float mu = s * (1.0f / 768.0f);
    float c0 = v0 - mu, c1 = v1 - mu, c2 = v2 - mu;
    float ss = blockSum(c0 * c0 + c1 * c1 + c2 * c2, red);
    float sdv = sqrtf(ss / 767.0f);        // torch-style unbiased std (ddof=1)
    float inv = 1.0f / (sdv + 1e-5f);
    float n0 = c0 * inv, n1 = c1 * inv, n2 = c2 * inv;
    float* xo = xn + (size_t)r * DIM;
    xo[t] = n0; xo[t + 256] = n1; xo[t + 512] = n2;
    u16* xb = xnb + (size_t)r * DIM;
    xb[t] = f2bf(n0); xb[t + 256] = f2bf(n1); xb[t + 512] = f2bf(n2);
    if (t == 0) { mean[r] = mu; sd[r] = sdv; }
}

// ---------------------------------------------------------------- W_enc transpose (+bf16)
__global__ __launch_bounds__(256) void k_transpose(const float* __restrict__ We,
                                                   float* __restrict__ WeT, u16* __restrict__ WeTb) {
    __shared__ float tile[32][33];
    int kt = blockIdx.x * 32, nt = blockIdx.y * 32;
    int tx = threadIdx.x & 31, ty = threadIdx.x >> 5;   // 32 x 8
    #pragma unroll
    for (int q = 0; q < 4; q++) {
        int row = ty + q * 8;
        tile[row][tx] = We[(size_t)(kt + row) * DICT + nt + tx];
    }
    __syncthreads();
    #pragma unroll
    for (int q = 0; q < 4; q++) {
        int row = ty + q * 8;
        float v = tile[tx][row];                         // We[kt+tx][nt+row]
        size_t o = (size_t)(nt + row) * DIM + kt + tx;
        WeT[o] = v;
        WeTb[o] = f2bf(v);
    }
}

// ---------------------------------------------------------------- W_dec -> bf16
__global__ __launch_bounds__(256) void k_castdec(const float* __restrict__ Wd, u16* __restrict__ Wdb) {
    const size_t n4 = (size_t)DICT * DIM / 4;
    for (size_t i = (size_t)blockIdx.x * 256 + threadIdx.x; i < n4; i += (size_t)gridDim.x * 256) {
        float4 v = ((const float4*)Wd)[i];
        ((ushort4*)Wdb)[i] = make_ushort4(f2bf(v.x), f2bf(v.y), f2bf(v.z), f2bf(v.w));
    }
}

// ---------------------------------------------------------------- enc bias = b_dec @ W_enc
__global__ __launch_bounds__(256) void k_encbias(const float* __restrict__ bdec,
                                                 const float* __restrict__ We, float* __restrict__ eb) {
    int c = blockIdx.x * 256 + threadIdx.x;
    int k0 = blockIdx.y * 96;
    float s = 0.f;
    for (int k = k0; k < k0 + 96; k++) s += bdec[k] * We[(size_t)k * DICT + c];
    if (s != 0.f) atomicAdd(&eb[c], s);
}

// ---------------------------------------------------------------- bf16 MFMA GEMM (m97 structure)
// acts_approx = relu(xn @ W_enc - eb), stored bf16
__global__ __launch_bounds__(256) void k_gemm(const u16* __restrict__ A,   // xn bf16 [NB][DIM]
                                              const u16* __restrict__ B,   // WencT bf16 [DICT][DIM]
                                              const float* __restrict__ eb,
                                              u16* __restrict__ C) {
    __shared__ __align__(16) u16 As[128 * 32];
    __shared__ __align__(16) u16 Bs[128 * 32];
    const int K = DIM;
    int tid = threadIdx.x, lane = tid & 63, wave = tid >> 6;
    int m0 = blockIdx.y * 128, n0 = blockIdx.x * 128;
    int wm = (wave >> 1) * 64, wn = (wave & 1) * 64;
    int lrow = lane >> 2, lkq = (lane & 3) * 8;

    const u16* gA = A + (size_t)(m0 + wave * 32 + lrow) * K + lkq;
    const u16* gB = B + (size_t)(n0 + wave * 32 + lrow) * K + lkq;
    u16* lA0 = &As[(wave * 32) * 32];
    u16* lA1 = &As[(wave * 32 + 16) * 32];
    u16* lB0 = &Bs[(wave * 32) * 32];
    u16* lB1 = &Bs[(wave * 32 + 16) * 32];

    f32x4 acc[4][4];
    #pragma unroll
    for (int m = 0; m < 4; m++)
        #pragma unroll
        for (int n = 0; n < 4; n++)
            #pragma unroll
            for (int q = 0; q < 4; q++) acc[m][n][q] = 0.f;

    int fr = lane & 15, fk = (lane >> 4) * 8;
    for (int kt = 0; kt < K; kt += 32) {
        __builtin_amdgcn_global_load_lds((const __attribute__((address_space(1))) void*)(gA + kt),
                                         (__attribute__((address_space(3))) void*)lA0, 16, 0, 0);
        __builtin_amdgcn_global_load_lds((const __attribute__((address_space(1))) void*)(gA + (size_t)16 * K + kt),
                                         (__attribute__((address_space(3))) void*)lA1, 16, 0, 0);
        __builtin_amdgcn_global_load_lds((const __attribute__((address_space(1))) void*)(gB + kt),
                                         (__attribute__((address_space(3))) void*)lB0, 16, 0, 0);
        __builtin_amdgcn_global_load_lds((const __attribute__((address_space(1))) void*)(gB + (size_t)16 * K + kt),
                                         (__attribute__((address_space(3))) void*)lB1, 16, 0, 0);
        __syncthreads();
        short8 af[4], bfr[4];
        #pragma unroll
        for (int m = 0; m < 4; m++) af[m] = *(const short8*)&As[(wm + m * 16 + fr) * 32 + fk];
        #pragma unroll
        for (int n = 0; n < 4; n++) bfr[n] = *(const short8*)&Bs[(wn + n * 16 + fr) * 32 + fk];
        #pragma unroll
        for (int m = 0; m < 4; m++)
            #pragma unroll
            for (int n = 0; n < 4; n++)
                acc[m][n] = __builtin_amdgcn_mfma_f32_16x16x32_bf16(af[m], bfr[n], acc[m][n], 0, 0, 0);
        __syncthreads();
    }

    int fg = lane >> 4;
    #pragma unroll
    for (int m = 0; m < 4; m++) {
        #pragma unroll
        for (int n = 0; n < 4; n++) {
            int gcol = n0 + wn + n * 16 + fr;
            float ebv = eb[gcol];
            #pragma unroll
            for (int q = 0; q < 4; q++) {
                int grow = m0 + wm + m * 16 + fg * 4 + q;   // C/D layout (m89)
                float v = acc[m][n][q] - ebv;
                C[(size_t)grow * DICT + gcol] = f2bf(v > 0.f ? v : 0.f);
            }
        }
    }
}

// ---------------------------------------------------------------- per-row selection
// 11-bit radix key on bf16 bits (non-negative -> order-preserving)
__device__ void find_thresh(u32* hist, u32* sscan, u32* sctr, u32 K) {
    int tid = threadIdx.x;
    u32 s = 0;
    #pragma unroll
    for (int b = 0; b < 8; b++) s += hist[tid * 8 + b];
    sscan[tid] = s;
    __syncthreads();
    for (int off = 1; off < 256; off <<= 1) {
        u32 y = (tid + off < 256) ? sscan[tid + off] : 0u;
        __syncthreads();
        sscan[tid] += y;
        __syncthreads();
    }
    u32 cum = sscan[tid] - s;   // count strictly above own chunk
    for (int b = 7; b >= 0; b--) {
        u32 h = hist[tid * 8 + b];
        if (h && cum < K && cum + h >= K) { sctr[2] = tid * 8 + b; sctr[3] = cum; }
        cum += h;
    }
}

__device__ void bitonic_desc1024(u32* a) {
    int tid = threadIdx.x;
    for (u32 size = 2; size <= 1024; size <<= 1) {
        for (u32 stride = size >> 1; stride > 0; stride >>= 1) {
            __syncthreads();
            for (u32 t = tid; t < 512; t += 256) {
                u32 lo = 2 * t - (t & (stride - 1));
                u32 hi = lo + stride;
                bool desc = (lo & size) == 0;
                u32 x = a[lo], y = a[hi];
                if (desc ? (x < y) : (x > y)) { a[lo] = y; a[hi] = x; }
            }
        }
    }
    __syncthreads();
}

__global__ __launch_bounds__(256) void k_select(const u16* __restrict__ acts, const u32* __restrict__ deadw,
                                                u16* __restrict__ enci, int* __restrict__ encc,
                                                float* __restrict__ auxv, int* __restrict__ auxi) {
    __shared__ __align__(16) u16 sa[DICT];   // 48KB
    __shared__ u32 hist[2048];
    __shared__ u32 slist[1024];
    __shared__ u32 sscan[256];
    __shared__ u32 sctr[4];                  // 0:list 1:definite 2:bstar 3:chi
    int r = blockIdx.x, tid = threadIdx.x;

    { const uint4* src = (const uint4*)(acts + (size_t)r * DICT);
      uint4* dst = (uint4*)sa;
      for (int i = tid; i < DICT / 8; i += 256) dst[i] = src[i]; }

    // ----- pass 1: encoder candidate set, exactly KENC by approx value -----
    for (int i = tid; i < 2048; i += 256) hist[i] = 0;
    if (tid < 4) sctr[tid] = 0;
    __syncthreads();
    for (int i = tid; i < DICT; i += 256) { u32 v = sa[i]; if (v >= 32) atomicAdd(&hist[v >> 5], 1u); }
    __syncthreads();
    find_thresh(hist, sscan, sctr, KENC);
    __syncthreads();
    u32 bstar = sctr[2], chi = sctr[3];
    for (int i = tid; i < DICT; i += 256) {
        u32 v = sa[i], key = v >> 5;
        if (key == 0) continue;
        if (key > bstar) { u32 p = atomicAdd(&sctr[1], 1u); if (p < KENC) enci[r * KENC + p] = (u16)i; }
        else if (key == bstar) { u32 q = atomicAdd(&sctr[0], 1u); if (q < 1024) slist[q] = (v << 16) | (0x7FFFu - (u32)i); }
    }
    __syncthreads();
    { u32 lc = sctr[0]; if (lc > 1024) lc = 1024;
      for (int i = tid + lc; i < 1024; i += 256) slist[i] = 0; }
    bitonic_desc1024(slist);
    { int need = (int)KENC - (int)chi;
      for (int t2 = tid; t2 < need; t2 += 256) {
          u32 e = slist[t2];
          enci[r * KENC + chi + t2] = (u16)(e ? (0x7FFFu - (e & 0xFFFFu)) : 0u);
      }
      if (tid == 0) encc[r] = KENC; }
    __syncthreads();

    // ----- pass 2: aux top-TKA among dead features -----
    for (int i = tid; i < 2048; i += 256) hist[i] = 0;
    if (tid < 4) sctr[tid] = 0;
    __syncthreads();
    for (int i = tid; i < DICT; i += 256) {
        if (!((deadw[i >> 5] >> (i & 31)) & 1u)) continue;
        u32 v = sa[i]; if (v >= 32) atomicAdd(&hist[v >> 5], 1u);
    }
    __syncthreads();
    find_thresh(hist, sscan, sctr, TKA);
    __syncthreads();
    bstar = sctr[2]; chi = sctr[3];
    for (int i = tid; i < DICT; i += 256) {
        if (!((deadw[i >> 5] >> (i & 31)) & 1u)) continue;
        u32 v = sa[i], key = v >> 5;
        if (key == 0) continue;
        if (key > bstar) {
            u32 p = atomicAdd(&sctr[1], 1u);
            if (p < TKA) { auxv[r * TKA + p] = bf2f((u16)v); auxi[r * TKA + p] = i; }
        } else if (key == bstar) {
            u32 q = atomicAdd(&sctr[0], 1u);
            if (q < 1024) slist[q] = (v << 16) | (0x7FFFu - (u32)i);
        }
    }
    __syncthreads();
    { u32 lc = sctr[0]; if (lc > 1024) lc = 1024;
      for (int i = tid + lc; i < 1024; i += 256) slist[i] = 0; }
    bitonic_desc1024(slist);
    { u32 cA = sctr[1]; if (cA > TKA) cA = TKA;
      int need = (int)TKA - (int)cA;
      for (int t2 = tid; t2 < need; t2 += 256) {
          u32 e = slist[t2];
          if (e) { auxv[r * TKA + cA + t2] = bf2f((u16)(e >> 16)); auxi[r * TKA + cA + t2] = (int)(0x7FFFu - (e & 0xFFFFu)); }
          else   { auxv[r * TKA + cA + t2] = 0.f; auxi[r * TKA + cA + t2] = 0; }
      }
    }
}

// ---------------------------------------------------------------- exact recompute of enc candidates + top-32
__global__ __launch_bounds__(256) void k_recompute(const float* __restrict__ xn, const float* __restrict__ WeT,
                                                   const float* __restrict__ eb,
                                                   const u16* __restrict__ enci, const int* __restrict__ encc,
                                                   float* __restrict__ tkv, int* __restrict__ tki, int* __restrict__ tkc) {
    __shared__ float sxn[DIM];
    __shared__ float cval[KENC];
    __shared__ u16 cidx[KENC];
    int r = blockIdx.x, tid = threadIdx.x, lane = tid & 63, wave = tid >> 6;
    for (int i = tid; i < DIM; i += 256) sxn[i] = xn[(size_t)r * DIM + i];
    int n = encc[r]; if (n > KENC) n = KENC;
    if (tid < KENC) cidx[tid] = (tid < n) ? enci[r * KENC + tid] : (u16)0;
    __syncthreads();
    for (int c = wave; c < n; c += 4) {
        int col = cidx[c];
        const float* wp = WeT + (size_t)col * DIM;
        double acc = 0.0;                       // f64: minimize our side of fp32 tie-noise
        #pragma unroll
        for (int j = 0; j < 12; j++) acc += (double)sxn[lane + j * 64] * (double)wp[lane + j * 64];
        #pragma unroll
        for (int o = 32; o; o >>= 1) acc += __shfl_xor(acc, o);
        if (lane == 0) { double v = acc - (double)eb[col]; cval[c] = (v > 0.0) ? (float)v : 0.f; }
    }
    __syncthreads();
    if (wave == 0) {
        u64 k0 = 0;
        if (lane < n) k0 = (((u64)__float_as_uint(cval[lane])) << 16) | (u64)(0xFFFFu - (u32)cidx[lane]);
        int written = 0;
        for (int it = 0; it < TK; it++) {
            u64 m = k0;
            #pragma unroll
            for (int o = 32; o; o >>= 1) { u64 x = __shfl_xor(m, o); if (x > m) m = x; }
            if (m == 0) break;
            if (k0 == m) k0 = 0;
            if (lane == 0) {
                tkv[r * TK + it] = __uint_as_float((u32)(m >> 16));
                tki[r * TK + it] = (int)(0xFFFFu - (u32)(m & 0xFFFFu));
            }
            written++;
        }
        if (lane == 0) {
            tkc[r] = written;
            for (int it = written; it < TK; it++) { tkv[r * TK + it] = 0.f; tki[r * TK + it] = 0; }
        }
    }
}

// ---------------------------------------------------------------- dense zero + sparse scatter
__global__ __launch_bounds__(256) void k_zero(float4* __restrict__ p, size_t n4) {
    for (size_t i = (size_t)blockIdx.x * 256 + threadIdx.x; i < n4; i += (size_t)gridDim.x * 256)
        p[i] = make_float4(0.f, 0.f, 0.f, 0.f);
}
__global__ __launch_bounds__(256) void k_scatter(const float* __restrict__ tkv, const int* __restrict__ tki,
                                                 const int* __restrict__ tkc, float* __restrict__ acts_out) {
    int g = blockIdx.x * 256 + threadIdx.x;
    int r = g >> 5, j = g & 31;
    if (j < tkc[r]) acts_out[(size_t)r * DICT + tki[g]] = tkv[g];
}

// ---------------------------------------------------------------- decode + l2/l1/l0 + sae_out
__global__ __launch_bounds__(256) void k_decode(const float* __restrict__ tkv, const int* __restrict__ tki,
                                                const int* __restrict__ tkc,
                                                const float* __restrict__ Wdec, const float* __restrict__ bdec,
                                                const float* __restrict__ xn, const float* __restrict__ mean,
                                                const float* __restrict__ sd,
                                                float* __restrict__ xrec, float* __restrict__ sae,
                                                double* __restrict__ acc8) {
    __shared__ float sv[TK]; __shared__ int si[TK]; __shared__ float red[4];
    int r = blockIdx.x, t = threadIdx.x;
    int cnt = tkc[r];
    if (t < TK) { sv[t] = (t < cnt) ? tkv[r * TK + t] : 0.f; si[t] = (t < cnt) ? tki[r * TK + t] : 0; }
    __syncthreads();
    float a0 = 0, a1 = 0, a2 = 0;
    #pragma unroll 4
    for (int j = 0; j < TK; j++) {
        float v = sv[j]; const float* wp = Wdec + (size_t)si[j] * DIM;
        a0 = fmaf(v, wp[t], a0); a1 = fmaf(v, wp[t + 256], a1); a2 = fmaf(v, wp[t + 512], a2);
    }
    a0 += bdec[t]; a1 += bdec[t + 256]; a2 += bdec[t + 512];
    size_t ro = (size_t)r * DIM;
    xrec[ro + t] = a0; xrec[ro + t + 256] = a1; xrec[ro + t + 512] = a2;
    float mu = mean[r], sdv = sd[r];
    sae[ro + t] = a0 * sdv + mu; sae[ro + t + 256] = a1 * sdv + mu; sae[ro + t + 512] = a2 * sdv + mu;
    float x0 = xn[ro + t], x1 = xn[ro + t + 256], x2 = xn[ro + t + 512];
    float d0 = a0 - x0, d1 = a1 - x1, d2 = a2 - x2;
    float l2p = blockSum(d0 * d0 + d1 * d1 + d2 * d2, red);
    float l1p = blockSum((t < TK) ? sv[t] : 0.f, red);
    float l0p = blockSum((t < TK && sv[t] > 0.f) ? 1.f : 0.f, red);
    if (t == 0) {
        atomicAdd(&acc8[0], (double)l2p);
        atomicAdd(&acc8[1], (double)l1p);
        atomicAdd(&acc8[2], (double)l0p);
    }
}

// ---------------------------------------------------------------- aux loss
__global__ __launch_bounds__(256) void k_aux(const float* __restrict__ auxv, const int* __restrict__ auxi,
                                             const u16* __restrict__ Wdb,
                                             const float* __restrict__ xn, const float* __restrict__ xrec,
                                             double* __restrict__ acc8) {
    __shared__ float sv[TKA]; __shared__ int si[TKA]; __shared__ float red[4];
    int r = blockIdx.x, t = threadIdx.x;
    sv[t] = auxv[r * TKA + t]; si[t] = auxi[r * TKA + t];
    __syncthreads();
    float a0 = 0, a1 = 0, a2 = 0;
    #pragma unroll 4
    for (int j = 0; j < TKA; j++) {
        float v = sv[j]; const u16* wp = Wdb + (size_t)si[j] * DIM;
        a0 = fmaf(v, bf2f(wp[t]), a0); a1 = fmaf(v, bf2f(wp[t + 256]), a1); a2 = fmaf(v, bf2f(wp[t + 512]), a2);
    }
    size_t ro = (size_t)r * DIM;
    float r0 = xn[ro + t] - xrec[ro + t];
    float r1 = xn[ro + t + 256] - xrec[ro + t + 256];
    float r2 = xn[ro + t + 512] - xrec[ro + t + 512];
    float e0 = a0 - r0, e1 = a1 - r1, e2 = a2 - r2;
    float s = blockSum(e0 * e0 + e1 * e1 + e2 * e2, red);
    if (t == 0) atomicAdd(&acc8[3], (double)s);
}

// ---------------------------------------------------------------- cosine penalty
__global__ __launch_bounds__(256) void k_cos(const int* __restrict__ tki, const u16* __restrict__ Wdb,
                                             double* __restrict__ acc8) {
    __shared__ u16 sdec[TK * DIM];   // 48KB bf16 staging
    __shared__ int si[TK];
    __shared__ float red[4];
    int r = blockIdx.x, t = threadIdx.x, lane = t & 63, wave = t >> 6;
    if (t < TK) si[t] = tki[r * TK + t];
    __syncthreads();
    for (int q = t; q < TK * DIM; q += 256) {
        int row = q / DIM, col = q - row * DIM;
        sdec[q] = Wdb[(size_t)si[row] * DIM + col];
    }
    __syncthreads();
    float acc = 0.f;
    for (int p = wave; p < (TK * (TK - 1)) / 2; p += 4) {
        int i = 0, rem = p;
        while (rem >= TK - 1 - i) { rem -= TK - 1 - i; i++; }
        int j = i + 1 + rem;
        const u16* wi = &sdec[i * DIM]; const u16* wj = &sdec[j * DIM];
        float d = 0.f;
        #pragma unroll
        for (int q = 0; q < 12; q++) d += bf2f(wi[lane + q * 64]) * bf2f(wj[lane + q * 64]);
        d = waveSum(d);
        if (lane == 0) acc += fabsf(d);
    }
    float s = blockSum(acc, red);
    if (t == 0) atomicAdd(&acc8[4], (double)s);
}

// ---------------------------------------------------------------- scalars
__global__ void k_final(const double* __restrict__ acc8, float* __restrict__ outs) {
    if (threadIdx.x == 0 && blockIdx.x == 0) {
        double l2  = acc8[0] / ((double)NB * DIM);
        double l1n = acc8[1] / (double)NB;
        double l0  = acc8[2] / (double)NB;
        double l1l = 1e-4 * l1n;
        double aux = 0.03125 * (acc8[3] / ((double)NB * DIM));
        double ms  = 2.0 * acc8[4] / ((double)NB * TK * (TK - 1));
        double loss = l2 + l1l + aux + 0.01 * ms;
        outs[0] = (float)loss; outs[1] = (float)l2; outs[2] = (float)l1l;
        outs[3] = (float)l0;   outs[4] = (float)l1n; outs[5] = (float)aux;
        outs[6] = (float)ms;
    }
}

// ================================================================ host
extern "C" void kernel_launch(void* const* d_in, const int* in_sizes, int n_in,
                              void* d_out, int out_size, void* d_ws, size_t ws_size,
                              hipStream_t stream) {
    const float* x    = (const float*)d_in[0];
    const float* We   = (const float*)d_in[1];
    const float* Wd   = (const float*)d_in[2];
    const float* bdec = (const float*)d_in[3];
    const int*   nba  = (const int*)d_in[4];

    float* out      = (float*)d_out;
    float* sae      = out;                                  // [2048*768]
    float* acts_out = out + (size_t)NB * DIM;               // [2048*24576]
    float* scal     = out + (size_t)NB * DIM + (size_t)NB * DICT; // 7 scalars
    u16*   actsb    = (u16*)acts_out;                       // bf16 approx acts (100.7MB) staged in output region
    // f32 W_enc^T staged in the UNUSED upper part of the acts output region:
    // [106,954,752 .. 182,452,224) bytes into d_out — read by k_recompute, wiped by k_zero afterwards.
    float* WET      = (float*)((char*)d_out + 106954752);

    char* w = (char*)d_ws;                                  // total need ~96.3MB
    float*  XN   = (float*) (w + 0);
    u16*    XNB  = (u16*)   (w + 6291456);
    float*  MEAN = (float*) (w + 9437184);
    float*  SD   = (float*) (w + 9445376);
    u16*    WETB = (u16*)   (w + 9453568);
    u16*    WDB  = (u16*)   (w + 47202304);
    float*  EB   = (float*) (w + 84951040);
    u32*    DW   = (u32*)   (w + 85049344);
    u16*    ENCI = (u16*)   (w + 85052416);
    int*    ENCC = (int*)   (w + 85249024);
    float*  AUXV = (float*) (w + 85257216);
    int*    AUXI = (int*)   (w + 87354368);
    float*  TKV  = (float*) (w + 89451520);
    int*    TKI  = (int*)   (w + 89713664);
    int*    TKC  = (int*)   (w + 89975808);
    float*  XREC = (float*) (w + 89984000);
    double* ACC  = (double*)(w + 96275456);

    k_init     <<<dim3(96),            dim3(256), 0, stream>>>(ACC, DW, nba, EB);
    k_norm     <<<dim3(NB),            dim3(256), 0, stream>>>(x, XN, XNB, MEAN, SD);
    k_transpose<<<dim3(24, 768),       dim3(256), 0, stream>>>(We, WET, WETB);
    k_castdec  <<<dim3(4096),          dim3(256), 0, stream>>>(Wd, WDB);
    k_encbias  <<<dim3(96, 8),         dim3(256), 0, stream>>>(bdec, We, EB);
    k_gemm     <<<dim3(DICT/128, NB/128), dim3(256), 0, stream>>>(XNB, WETB, EB, actsb);
    k_select   <<<dim3(NB),            dim3(256), 0, stream>>>(actsb, DW, ENCI, ENCC, AUXV, AUXI);
    k_recompute<<<dim3(NB),            dim3(256), 0, stream>>>(XN, WET, EB, ENCI, ENCC, TKV, TKI, TKC);
    k_zero     <<<dim3(4096),          dim3(256), 0, stream>>>((float4*)acts_out, (size_t)NB * DICT / 4);
    k_scatter  <<<dim3(NB * TK / 256), dim3(256), 0, stream>>>(TKV, TKI, TKC, acts_out);
    k_decode   <<<dim3(NB),            dim3(256), 0, stream>>>(TKV, TKI, TKC, Wd, bdec, XN, MEAN, SD, XREC, sae, ACC);
    k_aux      <<<dim3(NB),            dim3(256), 0, stream>>>(AUXV, AUXI, WDB, XN, XREC, ACC);
    k_cos      <<<dim3(NB),            dim3(256), 0, stream>>>(TKI, WDB, ACC);
    k_final    <<<dim3(1),             dim3(1),   0, stream>>>(ACC, scal);
}

// Round 4
// 1311.648 us; speedup vs baseline: 1.1554x; 1.1554x over previous
//
#include <hip/hip_runtime.h>

// TopK-SAE forward, MI355X.
// R3 change: k_select rewritten as register-resident bisection (no LDS staging,
// no bitonic sort, no histogram atomics). Everything else unchanged from R2.
//  - normalize rows (f32) + bf16 copy
//  - bf16 MFMA GEMM (128x128 tile, global_load_lds w16) -> approx acts (bf16,
//    staged in the acts_topk output region which is rewritten later)
//  - k_select: per-row 16-pass threshold bisection in registers -> top-48(+ties)
//    enc candidates (cap 128), top-256 dead features for aux
//  - exact f64 recompute of enc candidates -> exact top-32
//  - sparse decode, aux decode (bf16 W_dec), cosine penalty, f64 atomic losses

typedef unsigned int u32;
typedef unsigned short u16;
typedef unsigned long long u64;
using short8 = __attribute__((ext_vector_type(8))) short;
using f32x4  = __attribute__((ext_vector_type(4))) float;
using u16x2  = __attribute__((ext_vector_type(2))) unsigned short;

#define NB    2048
#define DIM   768
#define DICT  24576
#define TK    32
#define TKA   256
#define ENC_K   48
#define ENC_CAP 128
#define TIE_CAP 512

#if defined(__has_builtin)
#if __has_builtin(__builtin_elementwise_sub_sat) && __has_builtin(__builtin_elementwise_min)
#define USE_PK 1
#endif
#endif

__device__ __forceinline__ u16 f2bf(float f) {
    u32 u = __float_as_uint(f);
    u32 r = (u + 0x7FFFu + ((u >> 16) & 1u)) >> 16;
    return (u16)r;
}
__device__ __forceinline__ float bf2f(u16 b) { return __uint_as_float(((u32)b) << 16); }

__device__ __forceinline__ float waveSum(float v) {
    #pragma unroll
    for (int o = 32; o; o >>= 1) v += __shfl_xor(v, o);
    return v;
}
__device__ __forceinline__ float blockSum(float v, float* red) {
    __syncthreads();
    v = waveSum(v);
    if ((threadIdx.x & 63) == 0) red[threadIdx.x >> 6] = v;
    __syncthreads();
    return red[0] + red[1] + red[2] + red[3];
}
__device__ __forceinline__ int blockSumI(int v, int* red) {
    __syncthreads();
    #pragma unroll
    for (int o = 32; o; o >>= 1) v += __shfl_xor(v, o);
    if ((threadIdx.x & 63) == 0) red[threadIdx.x >> 6] = v;
    __syncthreads();
    return red[0] + red[1] + red[2] + red[3];
}

// ---------------------------------------------------------------- init
__global__ __launch_bounds__(256) void k_init(double* acc8, u32* deadw,
                                              const int* __restrict__ nba, float* eb) {
    int t = blockIdx.x * 256 + threadIdx.x;
    if (t < 8) acc8[t] = 0.0;
    if (t < DICT / 32) {
        u32 w = 0;
        const int* p = nba + t * 32;
        #pragma unroll
        for (int b = 0; b < 32; b++) if (p[b] >= 5) w |= (1u << b);
        deadw[t] = w;
    }
    if (t < DICT) eb[t] = 0.f;
}

// ---------------------------------------------------------------- normalize
__global__ __launch_bounds__(256) void k_norm(const float* __restrict__ x,
                                              float* __restrict__ xn, u16* __restrict__ xnb,
                                              float* __restrict__ mean, float* __restrict__ sd) {
    __shared__ float red[4];
    int r = blockIdx.x, t = threadIdx.x;
    const float* xr = x + (size_t)r * DIM;
    float v0 = xr[t], v1 = xr[t + 256], v2 = xr[t + 512];
    float s = blockSum(v0 + v1 + v2, red);
    float mu = s * (1.0f / 768.0f);
    float c0 = v0 - mu, c1 = v1 - mu, c2 = v2 - mu;
    float ss = blockSum(c0 * c0 + c1 * c1 + c2 * c2, red);
    float sdv = sqrtf(ss / 767.0f);        // torch-style unbiased std (ddof=1)
    float inv = 1.0f / (sdv + 1e-5f);
    float n0 = c0 * inv, n1 = c1 * inv, n2 = c2 * inv;
    float* xo = xn + (size_t)r * DIM;
    xo[t] = n0; xo[t + 256] = n1; xo[t + 512] = n2;
    u16* xb = xnb + (size_t)r * DIM;
    xb[t] = f2bf(n0); xb[t + 256] = f2bf(n1); xb[t + 512] = f2bf(n2);
    if (t == 0) { mean[r] = mu; sd[r] = sdv; }
}

// ---------------------------------------------------------------- W_enc transpose (+bf16)
__global__ __launch_bounds__(256) void k_transpose(const float* __restrict__ We,
                                                   float* __restrict__ WeT, u16* __restrict__ WeTb) {
    __shared__ float tile[32][33];
    int kt = blockIdx.x * 32, nt = blockIdx.y * 32;
    int tx = threadIdx.x & 31, ty = threadIdx.x >> 5;   // 32 x 8
    #pragma unroll
    for (int q = 0; q < 4; q++) {
        int row = ty + q * 8;
        tile[row][tx] = We[(size_t)(kt + row) * DICT + nt + tx];
    }
    __syncthreads();
    #pragma unroll
    for (int q = 0; q < 4; q++) {
        int row = ty + q * 8;
        float v = tile[tx][row];                         // We[kt+tx][nt+row]
        size_t o = (size_t)(nt + row) * DIM + kt + tx;
        WeT[o] = v;
        WeTb[o] = f2bf(v);
    }
}

// ---------------------------------------------------------------- W_dec -> bf16
__global__ __launch_bounds__(256) void k_castdec(const float* __restrict__ Wd, u16* __restrict__ Wdb) {
    const size_t n4 = (size_t)DICT * DIM / 4;
    for (size_t i = (size_t)blockIdx.x * 256 + threadIdx.x; i < n4; i += (size_t)gridDim.x * 256) {
        float4 v = ((const float4*)Wd)[i];
        ((ushort4*)Wdb)[i] = make_ushort4(f2bf(v.x), f2bf(v.y), f2bf(v.z), f2bf(v.w));
    }
}

// ---------------------------------------------------------------- enc bias = b_dec @ W_enc
__global__ __launch_bounds__(256) void k_encbias(const float* __restrict__ bdec,
                                                 const float* __restrict__ We, float* __restrict__ eb) {
    int c = blockIdx.x * 256 + threadIdx.x;
    int k0 = blockIdx.y * 96;
    float s = 0.f;
    for (int k = k0; k < k0 + 96; k++) s += bdec[k] * We[(size_t)k * DICT + c];
    if (s != 0.f) atomicAdd(&eb[c], s);
}

// ---------------------------------------------------------------- bf16 MFMA GEMM (m97 structure)
// acts_approx = relu(xn @ W_enc - eb), stored bf16
__global__ __launch_bounds__(256) void k_gemm(const u16* __restrict__ A,   // xn bf16 [NB][DIM]
                                              const u16* __restrict__ B,   // WencT bf16 [DICT][DIM]
                                              const float* __restrict__ eb,
                                              u16* __restrict__ C) {
    __shared__ __align__(16) u16 As[128 * 32];
    __shared__ __align__(16) u16 Bs[128 * 32];
    const int K = DIM;
    int tid = threadIdx.x, lane = tid & 63, wave = tid >> 6;
    int m0 = blockIdx.y * 128, n0 = blockIdx.x * 128;
    int wm = (wave >> 1) * 64, wn = (wave & 1) * 64;
    int lrow = lane >> 2, lkq = (lane & 3) * 8;

    const u16* gA = A + (size_t)(m0 + wave * 32 + lrow) * K + lkq;
    const u16* gB = B + (size_t)(n0 + wave * 32 + lrow) * K + lkq;
    u16* lA0 = &As[(wave * 32) * 32];
    u16* lA1 = &As[(wave * 32 + 16) * 32];
    u16* lB0 = &Bs[(wave * 32) * 32];
    u16* lB1 = &Bs[(wave * 32 + 16) * 32];

    f32x4 acc[4][4];
    #pragma unroll
    for (int m = 0; m < 4; m++)
        #pragma unroll
        for (int n = 0; n < 4; n++)
            #pragma unroll
            for (int q = 0; q < 4; q++) acc[m][n][q] = 0.f;

    int fr = lane & 15, fk = (lane >> 4) * 8;
    for (int kt = 0; kt < K; kt += 32) {
        __builtin_amdgcn_global_load_lds((const __attribute__((address_space(1))) void*)(gA + kt),
                                         (__attribute__((address_space(3))) void*)lA0, 16, 0, 0);
        __builtin_amdgcn_global_load_lds((const __attribute__((address_space(1))) void*)(gA + (size_t)16 * K + kt),
                                         (__attribute__((address_space(3))) void*)lA1, 16, 0, 0);
        __builtin_amdgcn_global_load_lds((const __attribute__((address_space(1))) void*)(gB + kt),
                                         (__attribute__((address_space(3))) void*)lB0, 16, 0, 0);
        __builtin_amdgcn_global_load_lds((const __attribute__((address_space(1))) void*)(gB + (size_t)16 * K + kt),
                                         (__attribute__((address_space(3))) void*)lB1, 16, 0, 0);
        __syncthreads();
        short8 af[4], bfr[4];
        #pragma unroll
        for (int m = 0; m < 4; m++) af[m] = *(const short8*)&As[(wm + m * 16 + fr) * 32 + fk];
        #pragma unroll
        for (int n = 0; n < 4; n++) bfr[n] = *(const short8*)&Bs[(wn + n * 16 + fr) * 32 + fk];
        #pragma unroll
        for (int m = 0; m < 4; m++)
            #pragma unroll
            for (int n = 0; n < 4; n++)
                acc[m][n] = __builtin_amdgcn_mfma_f32_16x16x32_bf16(af[m], bfr[n], acc[m][n], 0, 0, 0);
        __syncthreads();
    }

    int fg = lane >> 4;
    #pragma unroll
    for (int m = 0; m < 4; m++) {
        #pragma unroll
        for (int n = 0; n < 4; n++) {
            int gcol = n0 + wn + n * 16 + fr;
            float ebv = eb[gcol];
            #pragma unroll
            for (int q = 0; q < 4; q++) {
                int grow = m0 + wm + m * 16 + fg * 4 + q;   // C/D layout (m89)
                float v = acc[m][n][q] - ebv;
                C[(size_t)grow * DICT + gcol] = f2bf(v > 0.f ? v : 0.f);
            }
        }
    }
}

// ---------------------------------------------------------------- per-row selection
// Register-resident bisection select. Row (24576 bf16) lives in 12 uint4/thread.
// Threshold = largest T with count(v >= T) >= K, found by successive bit setting
// (15 count passes on the u16-monotone positive-bf16 key space). One emit pass.
__global__ __launch_bounds__(256, 4) void k_select(const u16* __restrict__ acts,
                                                   const u32* __restrict__ deadw,
                                                   u16* __restrict__ enci, int* __restrict__ encc,
                                                   float* __restrict__ auxv, int* __restrict__ auxi) {
    __shared__ u32 sdead[DICT / 32];      // 3KB
    __shared__ int red[4];
    __shared__ u32 tlist[TIE_CAP];        // 2KB
    __shared__ u32 scnt[2];               // 0: definite count, 1: tie count
    const int r = blockIdx.x, t = threadIdx.x;

    uint4 d[12];
    {
        const uint4* rowp = (const uint4*)(acts + (size_t)r * DICT);
        #pragma unroll
        for (int j = 0; j < 12; j++) d[j] = rowp[t + 256 * j];
    }
    for (int i = t; i < DICT / 32; i += 256) sdead[i] = deadw[i];

    // count of values >= T2 among this thread's 96 (T2 >= 1)
    auto cnt96 = [&](u32 T2) -> int {
#ifdef USE_PK
        unsigned short tm1s = (unsigned short)(T2 - 1u);
        u16x2 tm1 = { tm1s, tm1s };
        u16x2 one = { 1, 1 };
        u16x2 acc = { 0, 0 };
        #pragma unroll
        for (int j = 0; j < 12; j++) {
            acc = acc + __builtin_elementwise_min(
                __builtin_elementwise_sub_sat(__builtin_bit_cast(u16x2, d[j].x), tm1), one);
            acc = acc + __builtin_elementwise_min(
                __builtin_elementwise_sub_sat(__builtin_bit_cast(u16x2, d[j].y), tm1), one);
            acc = acc + __builtin_elementwise_min(
                __builtin_elementwise_sub_sat(__builtin_bit_cast(u16x2, d[j].z), tm1), one);
            acc = acc + __builtin_elementwise_min(
                __builtin_elementwise_sub_sat(__builtin_bit_cast(u16x2, d[j].w), tm1), one);
        }
        return (int)acc.x + (int)acc.y;
#else
        int c = 0;
        #pragma unroll
        for (int j = 0; j < 12; j++) {
            u32 w;
            w = d[j].x; c += (int)((w & 0xffffu) >= T2) + (int)((w >> 16) >= T2);
            w = d[j].y; c += (int)((w & 0xffffu) >= T2) + (int)((w >> 16) >= T2);
            w = d[j].z; c += (int)((w & 0xffffu) >= T2) + (int)((w >> 16) >= T2);
            w = d[j].w; c += (int)((w & 0xffffu) >= T2) + (int)((w >> 16) >= T2);
        }
        return c;
#endif
    };

    // ----------------- encoder: threshold at rank ENC_K -----------------
    u32 T = 0;
    for (int bit = 14; bit >= 0; --bit) {
        u32 T2 = T | (1u << bit);
        if (blockSumI(cnt96(T2), red) >= ENC_K) T = T2;   // uniform decision
    }
    // (count strictly greater = definites, tracked by atomic counter below)

    if (t == 0) { scnt[0] = 0; scnt[1] = 0; }
    __syncthreads();
    #pragma unroll
    for (int j = 0; j < 12; j++) {
        u32 base = (u32)(t + 256 * j) * 8u;
        #pragma unroll
        for (int q = 0; q < 4; q++) {
            u32 w = q == 0 ? d[j].x : q == 1 ? d[j].y : q == 2 ? d[j].z : d[j].w;
            u32 vlo = w & 0xffffu, vhi = w >> 16;
            u32 ilo = base + 2u * q, ihi = ilo + 1u;
            if (vlo > T) { u32 p = atomicAdd(&scnt[0], 1u); enci[r * ENC_CAP + p] = (u16)ilo; }
            else if (vlo == T && T != 0) { u32 p = atomicAdd(&scnt[1], 1u); if (p < TIE_CAP) tlist[p] = ilo; }
            if (vhi > T) { u32 p = atomicAdd(&scnt[0], 1u); enci[r * ENC_CAP + p] = (u16)ihi; }
            else if (vhi == T && T != 0) { u32 p = atomicAdd(&scnt[1], 1u); if (p < TIE_CAP) tlist[p] = ihi; }
        }
    }
    __syncthreads();
    {
        u32 chi  = scnt[0];                               // < ENC_K by construction
        u32 avail = scnt[1]; if (avail > TIE_CAP) avail = TIE_CAP;
        u32 take = (u32)ENC_CAP - chi; if (take > avail) take = avail;
        for (u32 i2 = t; i2 < take; i2 += 256) enci[r * ENC_CAP + chi + i2] = (u16)tlist[i2];
        if (t == 0) encc[r] = (int)(chi + take);
    }
    __syncthreads();   // tlist reads done before aux reuse

    // ----------------- aux: mask registers to dead-only, rank TKA -----------------
    #pragma unroll
    for (int j = 0; j < 12; j++) {
        u32 g = (u32)(t + 256 * j);
        u32 m8 = (sdead[g >> 2] >> ((g & 3u) * 8u)) & 0xffu;
        d[j].x &= (((m8 >> 0) & 1u) * 0xffffu) | (((m8 >> 1) & 1u) * 0xffff0000u);
        d[j].y &= (((m8 >> 2) & 1u) * 0xffffu) | (((m8 >> 3) & 1u) * 0xffff0000u);
        d[j].z &= (((m8 >> 4) & 1u) * 0xffffu) | (((m8 >> 5) & 1u) * 0xffff0000u);
        d[j].w &= (((m8 >> 6) & 1u) * 0xffffu) | (((m8 >> 7) & 1u) * 0xffff0000u);
    }

    u32 Ta = 0;
    for (int bit = 14; bit >= 0; --bit) {
        u32 T2 = Ta | (1u << bit);
        if (blockSumI(cnt96(T2), red) >= TKA) Ta = T2;
    }

    if (t == 0) { scnt[0] = 0; scnt[1] = 0; }
    __syncthreads();
    #pragma unroll
    for (int j = 0; j < 12; j++) {
        u32 base = (u32)(t + 256 * j) * 8u;
        #pragma unroll
        for (int q = 0; q < 4; q++) {
            u32 w = q == 0 ? d[j].x : q == 1 ? d[j].y : q == 2 ? d[j].z : d[j].w;
            u32 vlo = w & 0xffffu, vhi = w >> 16;
            u32 ilo = base + 2u * q, ihi = ilo + 1u;
            if (vlo > Ta) { u32 p = atomicAdd(&scnt[0], 1u); auxi[r * TKA + p] = (int)ilo; auxv[r * TKA + p] = bf2f((u16)vlo); }
            else if (vlo == Ta && Ta != 0) { u32 p = atomicAdd(&scnt[1], 1u); if (p < TIE_CAP) tlist[p] = ilo; }
            if (vhi > Ta) { u32 p = atomicAdd(&scnt[0], 1u); auxi[r * TKA + p] = (int)ihi; auxv[r * TKA + p] = bf2f((u16)vhi); }
            else if (vhi == Ta && Ta != 0) { u32 p = atomicAdd(&scnt[1], 1u); if (p < TIE_CAP) tlist[p] = ihi; }
        }
    }
    __syncthreads();
    {
        u32 chia = scnt[0];                               // < TKA by construction
        u32 avail = (Ta != 0) ? scnt[1] : 0u; if (avail > TIE_CAP) avail = TIE_CAP;
        u32 need = (u32)TKA - chia;
        float tv = bf2f((u16)Ta);
        for (u32 i2 = t; i2 < need; i2 += 256) {
            if (i2 < avail) { auxi[r * TKA + chia + i2] = (int)tlist[i2]; auxv[r * TKA + chia + i2] = tv; }
            else            { auxi[r * TKA + chia + i2] = 0;              auxv[r * TKA + chia + i2] = 0.f; }
        }
    }
}

// ---------------------------------------------------------------- exact recompute of enc candidates + top-32
__global__ __launch_bounds__(256) void k_recompute(const float* __restrict__ xn, const float* __restrict__ WeT,
                                                   const float* __restrict__ eb,
                                                   const u16* __restrict__ enci, const int* __restrict__ encc,
                                                   float* __restrict__ tkv, int* __restrict__ tki, int* __restrict__ tkc) {
    __shared__ float sxn[DIM];
    __shared__ float cval[ENC_CAP];
    __shared__ u16 cidx[ENC_CAP];
    int r = blockIdx.x, tid = threadIdx.x, lane = tid & 63, wave = tid >> 6;
    for (int i = tid; i < DIM; i += 256) sxn[i] = xn[(size_t)r * DIM + i];
    int n = encc[r]; if (n > ENC_CAP) n = ENC_CAP; if (n < 0) n = 0;
    if (tid < ENC_CAP) cidx[tid] = (tid < n) ? enci[r * ENC_CAP + tid] : (u16)0;
    __syncthreads();
    for (int c = wave; c < n; c += 4) {
        int col = cidx[c];
        const float* wp = WeT + (size_t)col * DIM;
        double acc = 0.0;                       // f64: minimize our side of fp32 tie-noise
        #pragma unroll
        for (int j = 0; j < 12; j++) acc += (double)sxn[lane + j * 64] * (double)wp[lane + j * 64];
        #pragma unroll
        for (int o = 32; o; o >>= 1) acc += __shfl_xor(acc, o);
        if (lane == 0) { double v = acc - (double)eb[col]; cval[c] = (v > 0.0) ? (float)v : 0.f; }
    }
    __syncthreads();
    if (wave == 0) {
        u64 ka = 0, kb = 0;
        if (lane < n)      ka = (((u64)__float_as_uint(cval[lane]))      << 16) | (u64)(0xFFFFu - (u32)cidx[lane]);
        if (lane + 64 < n) kb = (((u64)__float_as_uint(cval[lane + 64])) << 16) | (u64)(0xFFFFu - (u32)cidx[lane + 64]);
        int written = 0;
        for (int it = 0; it < TK; it++) {
            u64 m = ka > kb ? ka : kb;
            #pragma unroll
            for (int o = 32; o; o >>= 1) { u64 x = __shfl_xor(m, o); if (x > m) m = x; }
            if (m == 0) break;
            if (ka == m) ka = 0; else if (kb == m) kb = 0;
            if (lane == 0) {
                tkv[r * TK + it] = __uint_as_float((u32)(m >> 16));
                tki[r * TK + it] = (int)(0xFFFFu - (u32)(m & 0xFFFFu));
            }
            written++;
        }
        if (lane == 0) {
            tkc[r] = written;
            for (int it = written; it < TK; it++) { tkv[r * TK + it] = 0.f; tki[r * TK + it] = 0; }
        }
    }
}

// ---------------------------------------------------------------- dense zero + sparse scatter
__global__ __launch_bounds__(256) void k_zero(float4* __restrict__ p, size_t n4) {
    for (size_t i = (size_t)blockIdx.x * 256 + threadIdx.x; i < n4; i += (size_t)gridDim.x * 256)
        p[i] = make_float4(0.f, 0.f, 0.f, 0.f);
}
__global__ __launch_bounds__(256) void k_scatter(const float* __restrict__ tkv, const int* __restrict__ tki,
                                                 const int* __restrict__ tkc, float* __restrict__ acts_out) {
    int g = blockIdx.x * 256 + threadIdx.x;
    int r = g >> 5, j = g & 31;
    if (j < tkc[r]) acts_out[(size_t)r * DICT + tki[g]] = tkv[g];
}

// ---------------------------------------------------------------- decode + l2/l1/l0 + sae_out
__global__ __launch_bounds__(256) void k_decode(const float* __restrict__ tkv, const int* __restrict__ tki,
                                                const int* __restrict__ tkc,
                                                const float* __restrict__ Wdec, const float* __restrict__ bdec,
                                                const float* __restrict__ xn, const float* __restrict__ mean,
                                                const float* __restrict__ sd,
                                                float* __restrict__ xrec, float* __restrict__ sae,
                                                double* __restrict__ acc8) {
    __shared__ float sv[TK]; __shared__ int si[TK]; __shared__ float red[4];
    int r = blockIdx.x, t = threadIdx.x;
    int cnt = tkc[r];
    if (t < TK) { sv[t] = (t < cnt) ? tkv[r * TK + t] : 0.f; si[t] = (t < cnt) ? tki[r * TK + t] : 0; }
    __syncthreads();
    float a0 = 0, a1 = 0, a2 = 0;
    #pragma unroll 4
    for (int j = 0; j < TK; j++) {
        float v = sv[j]; const float* wp = Wdec + (size_t)si[j] * DIM;
        a0 = fmaf(v, wp[t], a0); a1 = fmaf(v, wp[t + 256], a1); a2 = fmaf(v, wp[t + 512], a2);
    }
    a0 += bdec[t]; a1 += bdec[t + 256]; a2 += bdec[t + 512];
    size_t ro = (size_t)r * DIM;
    xrec[ro + t] = a0; xrec[ro + t + 256] = a1; xrec[ro + t + 512] = a2;
    float mu = mean[r], sdv = sd[r];
    sae[ro + t] = a0 * sdv + mu; sae[ro + t + 256] = a1 * sdv + mu; sae[ro + t + 512] = a2 * sdv + mu;
    float x0 = xn[ro + t], x1 = xn[ro + t + 256], x2 = xn[ro + t + 512];
    float d0 = a0 - x0, d1 = a1 - x1, d2 = a2 - x2;
    float l2p = blockSum(d0 * d0 + d1 * d1 + d2 * d2, red);
    float l1p = blockSum((t < TK) ? sv[t] : 0.f, red);
    float l0p = blockSum((t < TK && sv[t] > 0.f) ? 1.f : 0.f, red);
    if (t == 0) {
        atomicAdd(&acc8[0], (double)l2p);
        atomicAdd(&acc8[1], (double)l1p);
        atomicAdd(&acc8[2], (double)l0p);
    }
}

// ---------------------------------------------------------------- aux loss
__global__ __launch_bounds__(256) void k_aux(const float* __restrict__ auxv, const int* __restrict__ auxi,
                                             const u16* __restrict__ Wdb,
                                             const float* __restrict__ xn, const float* __restrict__ xrec,
                                             double* __restrict__ acc8) {
    __shared__ float sv[TKA]; __shared__ int si[TKA]; __shared__ float red[4];
    int r = blockIdx.x, t = threadIdx.x;
    sv[t] = auxv[r * TKA + t]; si[t] = auxi[r * TKA + t];
    __syncthreads();
    float a0 = 0, a1 = 0, a2 = 0;
    #pragma unroll 4
    for (int j = 0; j < TKA; j++) {
        float v = sv[j]; const u16* wp = Wdb + (size_t)si[j] * DIM;
        a0 = fmaf(v, bf2f(wp[t]), a0); a1 = fmaf(v, bf2f(wp[t + 256]), a1); a2 = fmaf(v, bf2f(wp[t + 512]), a2);
    }
    size_t ro = (size_t)r * DIM;
    float r0 = xn[ro + t] - xrec[ro + t];
    float r1 = xn[ro + t + 256] - xrec[ro + t + 256];
    float r2 = xn[ro + t + 512] - xrec[ro + t + 512];
    float e0 = a0 - r0, e1 = a1 - r1, e2 = a2 - r2;
    float s = blockSum(e0 * e0 + e1 * e1 + e2 * e2, red);
    if (t == 0) atomicAdd(&acc8[3], (double)s);
}

// ---------------------------------------------------------------- cosine penalty
__global__ __launch_bounds__(256) void k_cos(const int* __restrict__ tki, const u16* __restrict__ Wdb,
                                             double* __restrict__ acc8) {
    __shared__ u16 sdec[TK * DIM];   // 48KB bf16 staging
    __shared__ int si[TK];
    __shared__ float red[4];
    int r = blockIdx.x, t = threadIdx.x, lane = t & 63, wave = t >> 6;
    if (t < TK) si[t] = tki[r * TK + t];
    __syncthreads();
    for (int q = t; q < TK * DIM; q += 256) {
        int row = q / DIM, col = q - row * DIM;
        sdec[q] = Wdb[(size_t)si[row] * DIM + col];
    }
    __syncthreads();
    float acc = 0.f;
    for (int p = wave; p < (TK * (TK - 1)) / 2; p += 4) {
        int i = 0, rem = p;
        while (rem >= TK - 1 - i) { rem -= TK - 1 - i; i++; }
        int j = i + 1 + rem;
        const u16* wi = &sdec[i * DIM]; const u16* wj = &sdec[j * DIM];
        float d = 0.f;
        #pragma unroll
        for (int q = 0; q < 12; q++) d += bf2f(wi[lane + q * 64]) * bf2f(wj[lane + q * 64]);
        d = waveSum(d);
        if (lane == 0) acc += fabsf(d);
    }
    float s = blockSum(acc, red);
    if (t == 0) atomicAdd(&acc8[4], (double)s);
}

// ---------------------------------------------------------------- scalars
__global__ void k_final(const double* __restrict__ acc8, float* __restrict__ outs) {
    if (threadIdx.x == 0 && blockIdx.x == 0) {
        double l2  = acc8[0] / ((double)NB * DIM);
        double l1n = acc8[1] / (double)NB;
        double l0  = acc8[2] / (double)NB;
        double l1l = 1e-4 * l1n;
        double aux = 0.03125 * (acc8[3] / ((double)NB * DIM));
        double ms  = 2.0 * acc8[4] / ((double)NB * TK * (TK - 1));
        double loss = l2 + l1l + aux + 0.01 * ms;
        outs[0] = (float)loss; outs[1] = (float)l2; outs[2] = (float)l1l;
        outs[3] = (float)l0;   outs[4] = (float)l1n; outs[5] = (float)aux;
        outs[6] = (float)ms;
    }
}

// ================================================================ host
extern "C" void kernel_launch(void* const* d_in, const int* in_sizes, int n_in,
                              void* d_out, int out_size, void* d_ws, size_t ws_size,
                              hipStream_t stream) {
    const float* x    = (const float*)d_in[0];
    const float* We   = (const float*)d_in[1];
    const float* Wd   = (const float*)d_in[2];
    const float* bdec = (const float*)d_in[3];
    const int*   nba  = (const int*)d_in[4];

    float* out      = (float*)d_out;
    float* sae      = out;                                  // [2048*768]
    float* acts_out = out + (size_t)NB * DIM;               // [2048*24576]
    float* scal     = out + (size_t)NB * DIM + (size_t)NB * DICT; // 7 scalars
    u16*   actsb    = (u16*)acts_out;                       // bf16 approx acts staged in output region
    // f32 W_enc^T staged in the UNUSED upper part of the acts output region:
    // read by k_recompute, wiped by k_zero afterwards.
    float* WET      = (float*)((char*)d_out + 106954752);

    char* w = (char*)d_ws;                                  // total need ~96.6MB
    float*  XN   = (float*) (w + 0);
    u16*    XNB  = (u16*)   (w + 6291456);
    float*  MEAN = (float*) (w + 9437184);
    float*  SD   = (float*) (w + 9445376);
    u16*    WETB = (u16*)   (w + 9453568);
    u16*    WDB  = (u16*)   (w + 47202304);
    float*  EB   = (float*) (w + 84951040);
    u32*    DW   = (u32*)   (w + 85049344);
    u16*    ENCI = (u16*)   (w + 85052416);   // 2048*128*2 = 524288
    int*    ENCC = (int*)   (w + 85576704);
    float*  AUXV = (float*) (w + 85584896);
    int*    AUXI = (int*)   (w + 87682048);
    float*  TKV  = (float*) (w + 89779200);
    int*    TKI  = (int*)   (w + 90041344);
    int*    TKC  = (int*)   (w + 90303488);
    float*  XREC = (float*) (w + 90311680);
    double* ACC  = (double*)(w + 96603136);

    k_init     <<<dim3(96),            dim3(256), 0, stream>>>(ACC, DW, nba, EB);
    k_norm     <<<dim3(NB),            dim3(256), 0, stream>>>(x, XN, XNB, MEAN, SD);
    k_transpose<<<dim3(24, 768),       dim3(256), 0, stream>>>(We, WET, WETB);
    k_castdec  <<<dim3(4096),          dim3(256), 0, stream>>>(Wd, WDB);
    k_encbias  <<<dim3(96, 8),         dim3(256), 0, stream>>>(bdec, We, EB);
    k_gemm     <<<dim3(DICT/128, NB/128), dim3(256), 0, stream>>>(XNB, WETB, EB, actsb);
    k_select   <<<dim3(NB),            dim3(256), 0, stream>>>(actsb, DW, ENCI, ENCC, AUXV, AUXI);
    k_recompute<<<dim3(NB),            dim3(256), 0, stream>>>(XN, WET, EB, ENCI, ENCC, TKV, TKI, TKC);
    k_zero     <<<dim3(4096),          dim3(256), 0, stream>>>((float4*)acts_out, (size_t)NB * DICT / 4);
    k_scatter  <<<dim3(NB * TK / 256), dim3(256), 0, stream>>>(TKV, TKI, TKC, acts_out);
    k_decode   <<<dim3(NB),            dim3(256), 0, stream>>>(TKV, TKI, TKC, Wd, bdec, XN, MEAN, SD, XREC, sae, ACC);
    k_aux      <<<dim3(NB),            dim3(256), 0, stream>>>(AUXV, AUXI, WDB, XN, XREC, ACC);
    k_cos      <<<dim3(NB),            dim3(256), 0, stream>>>(TKI, WDB, ACC);
    k_final    <<<dim3(1),             dim3(1),   0, stream>>>(ACC, scal);
}

// Round 9
// 1091.160 us; speedup vs baseline: 1.3888x; 1.2021x over previous
//
#include <hip/hip_runtime.h>

// TopK-SAE forward, MI355X.
// R4 change (resubmitted — R5-R8 benches never acquired a GPU): k_cos
// rewritten as per-block 32x32 Gram matrix via bf16 MFMA (was: 496 serial
// pair-dots with per-pair wave shuffle-reduce, 350us, VALU-bound).
// k_final: cosine sum now covers both triangles -> drop the x2.
// R3: k_select register-bisection. Everything else unchanged.

typedef unsigned int u32;
typedef unsigned short u16;
typedef unsigned long long u64;
using short8 = __attribute__((ext_vector_type(8))) short;
using f32x4  = __attribute__((ext_vector_type(4))) float;
using u16x2  = __attribute__((ext_vector_type(2))) unsigned short;

#define NB    2048
#define DIM   768
#define DICT  24576
#define TK    32
#define TKA   256
#define ENC_K   48
#define ENC_CAP 128
#define TIE_CAP 512

#if defined(__has_builtin)
#if __has_builtin(__builtin_elementwise_sub_sat) && __has_builtin(__builtin_elementwise_min)
#define USE_PK 1
#endif
#endif

__device__ __forceinline__ u16 f2bf(float f) {
    u32 u = __float_as_uint(f);
    u32 r = (u + 0x7FFFu + ((u >> 16) & 1u)) >> 16;
    return (u16)r;
}
__device__ __forceinline__ float bf2f(u16 b) { return __uint_as_float(((u32)b) << 16); }

__device__ __forceinline__ float waveSum(float v) {
    #pragma unroll
    for (int o = 32; o; o >>= 1) v += __shfl_xor(v, o);
    return v;
}
__device__ __forceinline__ float blockSum(float v, float* red) {
    __syncthreads();
    v = waveSum(v);
    if ((threadIdx.x & 63) == 0) red[threadIdx.x >> 6] = v;
    __syncthreads();
    return red[0] + red[1] + red[2] + red[3];
}
__device__ __forceinline__ int blockSumI(int v, int* red) {
    __syncthreads();
    #pragma unroll
    for (int o = 32; o; o >>= 1) v += __shfl_xor(v, o);
    if ((threadIdx.x & 63) == 0) red[threadIdx.x >> 6] = v;
    __syncthreads();
    return red[0] + red[1] + red[2] + red[3];
}

// ---------------------------------------------------------------- init
__global__ __launch_bounds__(256) void k_init(double* acc8, u32* deadw,
                                              const int* __restrict__ nba, float* eb) {
    int t = blockIdx.x * 256 + threadIdx.x;
    if (t < 8) acc8[t] = 0.0;
    if (t < DICT / 32) {
        u32 w = 0;
        const int* p = nba + t * 32;
        #pragma unroll
        for (int b = 0; b < 32; b++) if (p[b] >= 5) w |= (1u << b);
        deadw[t] = w;
    }
    if (t < DICT) eb[t] = 0.f;
}

// ---------------------------------------------------------------- normalize
__global__ __launch_bounds__(256) void k_norm(const float* __restrict__ x,
                                              float* __restrict__ xn, u16* __restrict__ xnb,
                                              float* __restrict__ mean, float* __restrict__ sd) {
    __shared__ float red[4];
    int r = blockIdx.x, t = threadIdx.x;
    const float* xr = x + (size_t)r * DIM;
    float v0 = xr[t], v1 = xr[t + 256], v2 = xr[t + 512];
    float s = blockSum(v0 + v1 + v2, red);
    float mu = s * (1.0f / 768.0f);
    float c0 = v0 - mu, c1 = v1 - mu, c2 = v2 - mu;
    float ss = blockSum(c0 * c0 + c1 * c1 + c2 * c2, red);
    float sdv = sqrtf(ss / 767.0f);        // torch-style unbiased std (ddof=1)
    float inv = 1.0f / (sdv + 1e-5f);
    float n0 = c0 * inv, n1 = c1 * inv, n2 = c2 * inv;
    float* xo = xn + (size_t)r * DIM;
    xo[t] = n0; xo[t + 256] = n1; xo[t + 512] = n2;
    u16* xb = xnb + (size_t)r * DIM;
    xb[t] = f2bf(n0); xb[t + 256] = f2bf(n1); xb[t + 512] = f2bf(n2);
    if (t == 0) { mean[r] = mu; sd[r] = sdv; }
}

// ---------------------------------------------------------------- W_enc transpose (+bf16)
__global__ __launch_bounds__(256) void k_transpose(const float* __restrict__ We,
                                                   float* __restrict__ WeT, u16* __restrict__ WeTb) {
    __shared__ float tile[32][33];
    int kt = blockIdx.x * 32, nt = blockIdx.y * 32;
    int tx = threadIdx.x & 31, ty = threadIdx.x >> 5;   // 32 x 8
    #pragma unroll
    for (int q = 0; q < 4; q++) {
        int row = ty + q * 8;
        tile[row][tx] = We[(size_t)(kt + row) * DICT + nt + tx];
    }
    __syncthreads();
    #pragma unroll
    for (int q = 0; q < 4; q++) {
        int row = ty + q * 8;
        float v = tile[tx][row];                         // We[kt+tx][nt+row]
        size_t o = (size_t)(nt + row) * DIM + kt + tx;
        WeT[o] = v;
        WeTb[o] = f2bf(v);
    }
}

// ---------------------------------------------------------------- W_dec -> bf16
__global__ __launch_bounds__(256) void k_castdec(const float* __restrict__ Wd, u16* __restrict__ Wdb) {
    const size_t n4 = (size_t)DICT * DIM / 4;
    for (size_t i = (size_t)blockIdx.x * 256 + threadIdx.x; i < n4; i += (size_t)gridDim.x * 256) {
        float4 v = ((const float4*)Wd)[i];
        ((ushort4*)Wdb)[i] = make_ushort4(f2bf(v.x), f2bf(v.y), f2bf(v.z), f2bf(v.w));
    }
}

// ---------------------------------------------------------------- enc bias = b_dec @ W_enc
__global__ __launch_bounds__(256) void k_encbias(const float* __restrict__ bdec,
                                                 const float* __restrict__ We, float* __restrict__ eb) {
    int c = blockIdx.x * 256 + threadIdx.x;
    int k0 = blockIdx.y * 96;
    float s = 0.f;
    for (int k = k0; k < k0 + 96; k++) s += bdec[k] * We[(size_t)k * DICT + c];
    if (s != 0.f) atomicAdd(&eb[c], s);
}

// ---------------------------------------------------------------- bf16 MFMA GEMM (m97 structure)
// acts_approx = relu(xn @ W_enc - eb), stored bf16
__global__ __launch_bounds__(256) void k_gemm(const u16* __restrict__ A,   // xn bf16 [NB][DIM]
                                              const u16* __restrict__ B,   // WencT bf16 [DICT][DIM]
                                              const float* __restrict__ eb,
                                              u16* __restrict__ C) {
    __shared__ __align__(16) u16 As[128 * 32];
    __shared__ __align__(16) u16 Bs[128 * 32];
    const int K = DIM;
    int tid = threadIdx.x, lane = tid & 63, wave = tid >> 6;
    int m0 = blockIdx.y * 128, n0 = blockIdx.x * 128;
    int wm = (wave >> 1) * 64, wn = (wave & 1) * 64;
    int lrow = lane >> 2, lkq = (lane & 3) * 8;

    const u16* gA = A + (size_t)(m0 + wave * 32 + lrow) * K + lkq;
    const u16* gB = B + (size_t)(n0 + wave * 32 + lrow) * K + lkq;
    u16* lA0 = &As[(wave * 32) * 32];
    u16* lA1 = &As[(wave * 32 + 16) * 32];
    u16* lB0 = &Bs[(wave * 32) * 32];
    u16* lB1 = &Bs[(wave * 32 + 16) * 32];

    f32x4 acc[4][4];
    #pragma unroll
    for (int m = 0; m < 4; m++)
        #pragma unroll
        for (int n = 0; n < 4; n++)
            #pragma unroll
            for (int q = 0; q < 4; q++) acc[m][n][q] = 0.f;

    int fr = lane & 15, fk = (lane >> 4) * 8;
    for (int kt = 0; kt < K; kt += 32) {
        __builtin_amdgcn_global_load_lds((const __attribute__((address_space(1))) void*)(gA + kt),
                                         (__attribute__((address_space(3))) void*)lA0, 16, 0, 0);
        __builtin_amdgcn_global_load_lds((const __attribute__((address_space(1))) void*)(gA + (size_t)16 * K + kt),
                                         (__attribute__((address_space(3))) void*)lA1, 16, 0, 0);
        __builtin_amdgcn_global_load_lds((const __attribute__((address_space(1))) void*)(gB + kt),
                                         (__attribute__((address_space(3))) void*)lB0, 16, 0, 0);
        __builtin_amdgcn_global_load_lds((const __attribute__((address_space(1))) void*)(gB + (size_t)16 * K + kt),
                                         (__attribute__((address_space(3))) void*)lB1, 16, 0, 0);
        __syncthreads();
        short8 af[4], bfr[4];
        #pragma unroll
        for (int m = 0; m < 4; m++) af[m] = *(const short8*)&As[(wm + m * 16 + fr) * 32 + fk];
        #pragma unroll
        for (int n = 0; n < 4; n++) bfr[n] = *(const short8*)&Bs[(wn + n * 16 + fr) * 32 + fk];
        #pragma unroll
        for (int m = 0; m < 4; m++)
            #pragma unroll
            for (int n = 0; n < 4; n++)
                acc[m][n] = __builtin_amdgcn_mfma_f32_16x16x32_bf16(af[m], bfr[n], acc[m][n], 0, 0, 0);
        __syncthreads();
    }

    int fg = lane >> 4;
    #pragma unroll
    for (int m = 0; m < 4; m++) {
        #pragma unroll
        for (int n = 0; n < 4; n++) {
            int gcol = n0 + wn + n * 16 + fr;
            float ebv = eb[gcol];
            #pragma unroll
            for (int q = 0; q < 4; q++) {
                int grow = m0 + wm + m * 16 + fg * 4 + q;   // C/D layout (m89)
                float v = acc[m][n][q] - ebv;
                C[(size_t)grow * DICT + gcol] = f2bf(v > 0.f ? v : 0.f);
            }
        }
    }
}

// ---------------------------------------------------------------- per-row selection
// Register-resident bisection select. Row (24576 bf16) lives in 12 uint4/thread.
__global__ __launch_bounds__(256, 4) void k_select(const u16* __restrict__ acts,
                                                   const u32* __restrict__ deadw,
                                                   u16* __restrict__ enci, int* __restrict__ encc,
                                                   float* __restrict__ auxv, int* __restrict__ auxi) {
    __shared__ u32 sdead[DICT / 32];      // 3KB
    __shared__ int red[4];
    __shared__ u32 tlist[TIE_CAP];        // 2KB
    __shared__ u32 scnt[2];               // 0: definite count, 1: tie count
    const int r = blockIdx.x, t = threadIdx.x;

    uint4 d[12];
    {
        const uint4* rowp = (const uint4*)(acts + (size_t)r * DICT);
        #pragma unroll
        for (int j = 0; j < 12; j++) d[j] = rowp[t + 256 * j];
    }
    for (int i = t; i < DICT / 32; i += 256) sdead[i] = deadw[i];

    auto cnt96 = [&](u32 T2) -> int {
#ifdef USE_PK
        unsigned short tm1s = (unsigned short)(T2 - 1u);
        u16x2 tm1 = { tm1s, tm1s };
        u16x2 one = { 1, 1 };
        u16x2 acc = { 0, 0 };
        #pragma unroll
        for (int j = 0; j < 12; j++) {
            acc = acc + __builtin_elementwise_min(
                __builtin_elementwise_sub_sat(__builtin_bit_cast(u16x2, d[j].x), tm1), one);
            acc = acc + __builtin_elementwise_min(
                __builtin_elementwise_sub_sat(__builtin_bit_cast(u16x2, d[j].y), tm1), one);
            acc = acc + __builtin_elementwise_min(
                __builtin_elementwise_sub_sat(__builtin_bit_cast(u16x2, d[j].z), tm1), one);
            acc = acc + __builtin_elementwise_min(
                __builtin_elementwise_sub_sat(__builtin_bit_cast(u16x2, d[j].w), tm1), one);
        }
        return (int)acc.x + (int)acc.y;
#else
        int c = 0;
        #pragma unroll
        for (int j = 0; j < 12; j++) {
            u32 w;
            w = d[j].x; c += (int)((w & 0xffffu) >= T2) + (int)((w >> 16) >= T2);
            w = d[j].y; c += (int)((w & 0xffffu) >= T2) + (int)((w >> 16) >= T2);
            w = d[j].z; c += (int)((w & 0xffffu) >= T2) + (int)((w >> 16) >= T2);
            w = d[j].w; c += (int)((w & 0xffffu) >= T2) + (int)((w >> 16) >= T2);
        }
        return c;
#endif
    };

    // ----------------- encoder: threshold at rank ENC_K -----------------
    u32 T = 0;
    for (int bit = 14; bit >= 0; --bit) {
        u32 T2 = T | (1u << bit);
        if (blockSumI(cnt96(T2), red) >= ENC_K) T = T2;   // uniform decision
    }

    if (t == 0) { scnt[0] = 0; scnt[1] = 0; }
    __syncthreads();
    #pragma unroll
    for (int j = 0; j < 12; j++) {
        u32 base = (u32)(t + 256 * j) * 8u;
        #pragma unroll
        for (int q = 0; q < 4; q++) {
            u32 w = q == 0 ? d[j].x : q == 1 ? d[j].y : q == 2 ? d[j].z : d[j].w;
            u32 vlo = w & 0xffffu, vhi = w >> 16;
            u32 ilo = base + 2u * q, ihi = ilo + 1u;
            if (vlo > T) { u32 p = atomicAdd(&scnt[0], 1u); enci[r * ENC_CAP + p] = (u16)ilo; }
            else if (vlo == T && T != 0) { u32 p = atomicAdd(&scnt[1], 1u); if (p < TIE_CAP) tlist[p] = ilo; }
            if (vhi > T) { u32 p = atomicAdd(&scnt[0], 1u); enci[r * ENC_CAP + p] = (u16)ihi; }
            else if (vhi == T && T != 0) { u32 p = atomicAdd(&scnt[1], 1u); if (p < TIE_CAP) tlist[p] = ihi; }
        }
    }
    __syncthreads();
    {
        u32 chi  = scnt[0];                               // < ENC_K by construction
        u32 avail = scnt[1]; if (avail > TIE_CAP) avail = TIE_CAP;
        u32 take = (u32)ENC_CAP - chi; if (take > avail) take = avail;
        for (u32 i2 = t; i2 < take; i2 += 256) enci[r * ENC_CAP + chi + i2] = (u16)tlist[i2];
        if (t == 0) encc[r] = (int)(chi + take);
    }
    __syncthreads();   // tlist reads done before aux reuse

    // ----------------- aux: mask registers to dead-only, rank TKA -----------------
    #pragma unroll
    for (int j = 0; j < 12; j++) {
        u32 g = (u32)(t + 256 * j);
        u32 m8 = (sdead[g >> 2] >> ((g & 3u) * 8u)) & 0xffu;
        d[j].x &= (((m8 >> 0) & 1u) * 0xffffu) | (((m8 >> 1) & 1u) * 0xffff0000u);
        d[j].y &= (((m8 >> 2) & 1u) * 0xffffu) | (((m8 >> 3) & 1u) * 0xffff0000u);
        d[j].z &= (((m8 >> 4) & 1u) * 0xffffu) | (((m8 >> 5) & 1u) * 0xffff0000u);
        d[j].w &= (((m8 >> 6) & 1u) * 0xffffu) | (((m8 >> 7) & 1u) * 0xffff0000u);
    }

    u32 Ta = 0;
    for (int bit = 14; bit >= 0; --bit) {
        u32 T2 = Ta | (1u << bit);
        if (blockSumI(cnt96(T2), red) >= TKA) Ta = T2;
    }

    if (t == 0) { scnt[0] = 0; scnt[1] = 0; }
    __syncthreads();
    #pragma unroll
    for (int j = 0; j < 12; j++) {
        u32 base = (u32)(t + 256 * j) * 8u;
        #pragma unroll
        for (int q = 0; q < 4; q++) {
            u32 w = q == 0 ? d[j].x : q == 1 ? d[j].y : q == 2 ? d[j].z : d[j].w;
            u32 vlo = w & 0xffffu, vhi = w >> 16;
            u32 ilo = base + 2u * q, ihi = ilo + 1u;
            if (vlo > Ta) { u32 p = atomicAdd(&scnt[0], 1u); auxi[r * TKA + p] = (int)ilo; auxv[r * TKA + p] = bf2f((u16)vlo); }
            else if (vlo == Ta && Ta != 0) { u32 p = atomicAdd(&scnt[1], 1u); if (p < TIE_CAP) tlist[p] = ilo; }
            if (vhi > Ta) { u32 p = atomicAdd(&scnt[0], 1u); auxi[r * TKA + p] = (int)ihi; auxv[r * TKA + p] = bf2f((u16)vhi); }
            else if (vhi == Ta && Ta != 0) { u32 p = atomicAdd(&scnt[1], 1u); if (p < TIE_CAP) tlist[p] = ihi; }
        }
    }
    __syncthreads();
    {
        u32 chia = scnt[0];                               // < TKA by construction
        u32 avail = (Ta != 0) ? scnt[1] : 0u; if (avail > TIE_CAP) avail = TIE_CAP;
        u32 need = (u32)TKA - chia;
        float tv = bf2f((u16)Ta);
        for (u32 i2 = t; i2 < need; i2 += 256) {
            if (i2 < avail) { auxi[r * TKA + chia + i2] = (int)tlist[i2]; auxv[r * TKA + chia + i2] = tv; }
            else            { auxi[r * TKA + chia + i2] = 0;              auxv[r * TKA + chia + i2] = 0.f; }
        }
    }
}

// ---------------------------------------------------------------- exact recompute of enc candidates + top-32
__global__ __launch_bounds__(256) void k_recompute(const float* __restrict__ xn, const float* __restrict__ WeT,
                                                   const float* __restrict__ eb,
                                                   const u16* __restrict__ enci, const int* __restrict__ encc,
                                                   float* __restrict__ tkv, int* __restrict__ tki, int* __restrict__ tkc) {
    __shared__ float sxn[DIM];
    __shared__ float cval[ENC_CAP];
    __shared__ u16 cidx[ENC_CAP];
    int r = blockIdx.x, tid = threadIdx.x, lane = tid & 63, wave = tid >> 6;
    for (int i = tid; i < DIM; i += 256) sxn[i] = xn[(size_t)r * DIM + i];
    int n = encc[r]; if (n > ENC_CAP) n = ENC_CAP; if (n < 0) n = 0;
    if (tid < ENC_CAP) cidx[tid] = (tid < n) ? enci[r * ENC_CAP + tid] : (u16)0;
    __syncthreads();
    for (int c = wave; c < n; c += 4) {
        int col = cidx[c];
        const float* wp = WeT + (size_t)col * DIM;
        double acc = 0.0;                       // f64: minimize our side of fp32 tie-noise
        #pragma unroll
        for (int j = 0; j < 12; j++) acc += (double)sxn[lane + j * 64] * (double)wp[lane + j * 64];
        #pragma unroll
        for (int o = 32; o; o >>= 1) acc += __shfl_xor(acc, o);
        if (lane == 0) { double v = acc - (double)eb[col]; cval[c] = (v > 0.0) ? (float)v : 0.f; }
    }
    __syncthreads();
    if (wave == 0) {
        u64 ka = 0, kb = 0;
        if (lane < n)      ka = (((u64)__float_as_uint(cval[lane]))      << 16) | (u64)(0xFFFFu - (u32)cidx[lane]);
        if (lane + 64 < n) kb = (((u64)__float_as_uint(cval[lane + 64])) << 16) | (u64)(0xFFFFu - (u32)cidx[lane + 64]);
        int written = 0;
        for (int it = 0; it < TK; it++) {
            u64 m = ka > kb ? ka : kb;
            #pragma unroll
            for (int o = 32; o; o >>= 1) { u64 x = __shfl_xor(m, o); if (x > m) m = x; }
            if (m == 0) break;
            if (ka == m) ka = 0; else if (kb == m) kb = 0;
            if (lane == 0) {
                tkv[r * TK + it] = __uint_as_float((u32)(m >> 16));
                tki[r * TK + it] = (int)(0xFFFFu - (u32)(m & 0xFFFFu));
            }
            written++;
        }
        if (lane == 0) {
            tkc[r] = written;
            for (int it = written; it < TK; it++) { tkv[r * TK + it] = 0.f; tki[r * TK + it] = 0; }
        }
    }
}

// ---------------------------------------------------------------- dense zero + sparse scatter
__global__ __launch_bounds__(256) void k_zero(float4* __restrict__ p, size_t n4) {
    for (size_t i = (size_t)blockIdx.x * 256 + threadIdx.x; i < n4; i += (size_t)gridDim.x * 256)
        p[i] = make_float4(0.f, 0.f, 0.f, 0.f);
}
__global__ __launch_bounds__(256) void k_scatter(const float* __restrict__ tkv, const int* __restrict__ tki,
                                                 const int* __restrict__ tkc, float* __restrict__ acts_out) {
    int g = blockIdx.x * 256 + threadIdx.x;
    int r = g >> 5, j = g & 31;
    if (j < tkc[r]) acts_out[(size_t)r * DICT + tki[g]] = tkv[g];
}

// ---------------------------------------------------------------- decode + l2/l1/l0 + sae_out
__global__ __launch_bounds__(256) void k_decode(const float* __restrict__ tkv, const int* __restrict__ tki,
                                                const int* __restrict__ tkc,
                                                const float* __restrict__ Wdec, const float* __restrict__ bdec,
                                                const float* __restrict__ xn, const float* __restrict__ mean,
                                                const float* __restrict__ sd,
                                                float* __restrict__ xrec, float* __restrict__ sae,
                                                double* __restrict__ acc8) {
    __shared__ float sv[TK]; __shared__ int si[TK]; __shared__ float red[4];
    int r = blockIdx.x, t = threadIdx.x;
    int cnt = tkc[r];
    if (t < TK) { sv[t] = (t < cnt) ? tkv[r * TK + t] : 0.f; si[t] = (t < cnt) ? tki[r * TK + t] : 0; }
    __syncthreads();
    float a0 = 0, a1 = 0, a2 = 0;
    #pragma unroll 4
    for (int j = 0; j < TK; j++) {
        float v = sv[j]; const float* wp = Wdec + (size_t)si[j] * DIM;
        a0 = fmaf(v, wp[t], a0); a1 = fmaf(v, wp[t + 256], a1); a2 = fmaf(v, wp[t + 512], a2);
    }
    a0 += bdec[t]; a1 += bdec[t + 256]; a2 += bdec[t + 512];
    size_t ro = (size_t)r * DIM;
    xrec[ro + t] = a0; xrec[ro + t + 256] = a1; xrec[ro + t + 512] = a2;
    float mu = mean[r], sdv = sd[r];
    sae[ro + t] = a0 * sdv + mu; sae[ro + t + 256] = a1 * sdv + mu; sae[ro + t + 512] = a2 * sdv + mu;
    float x0 = xn[ro + t], x1 = xn[ro + t + 256], x2 = xn[ro + t + 512];
    float d0 = a0 - x0, d1 = a1 - x1, d2 = a2 - x2;
    float l2p = blockSum(d0 * d0 + d1 * d1 + d2 * d2, red);
    float l1p = blockSum((t < TK) ? sv[t] : 0.f, red);
    float l0p = blockSum((t < TK && sv[t] > 0.f) ? 1.f : 0.f, red);
    if (t == 0) {
        atomicAdd(&acc8[0], (double)l2p);
        atomicAdd(&acc8[1], (double)l1p);
        atomicAdd(&acc8[2], (double)l0p);
    }
}

// ---------------------------------------------------------------- aux loss
__global__ __launch_bounds__(256) void k_aux(const float* __restrict__ auxv, const int* __restrict__ auxi,
                                             const u16* __restrict__ Wdb,
                                             const float* __restrict__ xn, const float* __restrict__ xrec,
                                             double* __restrict__ acc8) {
    __shared__ float sv[TKA]; __shared__ int si[TKA]; __shared__ float red[4];
    int r = blockIdx.x, t = threadIdx.x;
    sv[t] = auxv[r * TKA + t]; si[t] = auxi[r * TKA + t];
    __syncthreads();
    float a0 = 0, a1 = 0, a2 = 0;
    #pragma unroll 4
    for (int j = 0; j < TKA; j++) {
        float v = sv[j]; const u16* wp = Wdb + (size_t)si[j] * DIM;
        a0 = fmaf(v, bf2f(wp[t]), a0); a1 = fmaf(v, bf2f(wp[t + 256]), a1); a2 = fmaf(v, bf2f(wp[t + 512]), a2);
    }
    size_t ro = (size_t)r * DIM;
    float r0 = xn[ro + t] - xrec[ro + t];
    float r1 = xn[ro + t + 256] - xrec[ro + t + 256];
    float r2 = xn[ro + t + 512] - xrec[ro + t + 512];
    float e0 = a0 - r0, e1 = a1 - r1, e2 = a2 - r2;
    float s = blockSum(e0 * e0 + e1 * e1 + e2 * e2, red);
    if (t == 0) atomicAdd(&acc8[3], (double)s);
}

// ---------------------------------------------------------------- cosine penalty (MFMA Gram matrix)
// S = D * D^T for the 32 selected decoder rows (bf16, unit-norm). Full off-diag
// |S| sum (both triangles) -> k_final divides by NB*TK*(TK-1) with NO x2.
#define CPAD 8   // +8 bf16 -> row stride 1552B -> bank step 4 -> 2-way (free)
__global__ __launch_bounds__(256) void k_cos(const int* __restrict__ tki, const u16* __restrict__ Wdb,
                                             double* __restrict__ acc8) {
    __shared__ __align__(16) u16 sdec[TK][DIM + CPAD];   // ~48.5KB
    __shared__ int si[TK];
    __shared__ float red[4];
    int r = blockIdx.x, t = threadIdx.x, lane = t & 63, wave = t >> 6;
    if (t < TK) si[t] = tki[r * TK + t];
    __syncthreads();
    for (int idx = t; idx < TK * (DIM / 8); idx += 256) {
        int row = idx / (DIM / 8), c8 = idx - row * (DIM / 8);
        *(uint4*)&sdec[row][c8 * 8] = ((const uint4*)(Wdb + (size_t)si[row] * DIM))[c8];
    }
    __syncthreads();
    // wave quadrant: rows rbase..rbase+15, cols cbase..cbase+15
    int rbase = (wave >> 1) * 16, cbase = (wave & 1) * 16;
    int fr = lane & 15, fk = (lane >> 4) * 8;
    f32x4 acc = {0.f, 0.f, 0.f, 0.f};
    #pragma unroll 4
    for (int k0 = 0; k0 < DIM; k0 += 32) {
        short8 a = *(const short8*)&sdec[rbase + fr][k0 + fk];   // A row frag
        short8 b = *(const short8*)&sdec[cbase + fr][k0 + fk];   // B col frag (B=D^T)
        acc = __builtin_amdgcn_mfma_f32_16x16x32_bf16(a, b, acc, 0, 0, 0);
    }
    // C/D layout (m89): col = lane&15, row = (lane>>4)*4 + q
    float s = 0.f;
    #pragma unroll
    for (int q = 0; q < 4; q++) {
        int row = rbase + (lane >> 4) * 4 + q, col = cbase + fr;
        if (row != col) s += fabsf(acc[q]);
    }
    float tot = blockSum(s, red);
    if (t == 0) atomicAdd(&acc8[4], (double)tot);
}

// ---------------------------------------------------------------- scalars
__global__ void k_final(const double* __restrict__ acc8, float* __restrict__ outs) {
    if (threadIdx.x == 0 && blockIdx.x == 0) {
        double l2  = acc8[0] / ((double)NB * DIM);
        double l1n = acc8[1] / (double)NB;
        double l0  = acc8[2] / (double)NB;
        double l1l = 1e-4 * l1n;
        double aux = 0.03125 * (acc8[3] / ((double)NB * DIM));
        double ms  = acc8[4] / ((double)NB * TK * (TK - 1));   // full matrix summed, no x2
        double loss = l2 + l1l + aux + 0.01 * ms;
        outs[0] = (float)loss; outs[1] = (float)l2; outs[2] = (float)l1l;
        outs[3] = (float)l0;   outs[4] = (float)l1n; outs[5] = (float)aux;
        outs[6] = (float)ms;
    }
}

// ================================================================ host
extern "C" void kernel_launch(void* const* d_in, const int* in_sizes, int n_in,
                              void* d_out, int out_size, void* d_ws, size_t ws_size,
                              hipStream_t stream) {
    const float* x    = (const float*)d_in[0];
    const float* We   = (const float*)d_in[1];
    const float* Wd   = (const float*)d_in[2];
    const float* bdec = (const float*)d_in[3];
    const int*   nba  = (const int*)d_in[4];

    float* out      = (float*)d_out;
    float* sae      = out;                                  // [2048*768]
    float* acts_out = out + (size_t)NB * DIM;               // [2048*24576]
    float* scal     = out + (size_t)NB * DIM + (size_t)NB * DICT; // 7 scalars
    u16*   actsb    = (u16*)acts_out;                       // bf16 approx acts staged in output region
    // f32 W_enc^T staged in the UNUSED upper part of the acts output region:
    // read by k_recompute, wiped by k_zero afterwards.
    float* WET      = (float*)((char*)d_out + 106954752);

    char* w = (char*)d_ws;                                  // total need ~96.6MB
    float*  XN   = (float*) (w + 0);
    u16*    XNB  = (u16*)   (w + 6291456);
    float*  MEAN = (float*) (w + 9437184);
    float*  SD   = (float*) (w + 9445376);
    u16*    WETB = (u16*)   (w + 9453568);
    u16*    WDB  = (u16*)   (w + 47202304);
    float*  EB   = (float*) (w + 84951040);
    u32*    DW   = (u32*)   (w + 85049344);
    u16*    ENCI = (u16*)   (w + 85052416);   // 2048*128*2 = 524288
    int*    ENCC = (int*)   (w + 85576704);
    float*  AUXV = (float*) (w + 85584896);
    int*    AUXI = (int*)   (w + 87682048);
    float*  TKV  = (float*) (w + 89779200);
    int*    TKI  = (int*)   (w + 90041344);
    int*    TKC  = (int*)   (w + 90303488);
    float*  XREC = (float*) (w + 90311680);
    double* ACC  = (double*)(w + 96603136);

    k_init     <<<dim3(96),            dim3(256), 0, stream>>>(ACC, DW, nba, EB);
    k_norm     <<<dim3(NB),            dim3(256), 0, stream>>>(x, XN, XNB, MEAN, SD);
    k_transpose<<<dim3(24, 768),       dim3(256), 0, stream>>>(We, WET, WETB);
    k_castdec  <<<dim3(4096),          dim3(256), 0, stream>>>(Wd, WDB);
    k_encbias  <<<dim3(96, 8),         dim3(256), 0, stream>>>(bdec, We, EB);
    k_gemm     <<<dim3(DICT/128, NB/128), dim3(256), 0, stream>>>(XNB, WETB, EB, actsb);
    k_select   <<<dim3(NB),            dim3(256), 0, stream>>>(actsb, DW, ENCI, ENCC, AUXV, AUXI);
    k_recompute<<<dim3(NB),            dim3(256), 0, stream>>>(XN, WET, EB, ENCI, ENCC, TKV, TKI, TKC);
    k_zero     <<<dim3(4096),          dim3(256), 0, stream>>>((float4*)acts_out, (size_t)NB * DICT / 4);
    k_scatter  <<<dim3(NB * TK / 256), dim3(256), 0, stream>>>(TKV, TKI, TKC, acts_out);
    k_decode   <<<dim3(NB),            dim3(256), 0, stream>>>(TKV, TKI, TKC, Wd, bdec, XN, MEAN, SD, XREC, sae, ACC);
    k_aux      <<<dim3(NB),            dim3(256), 0, stream>>>(AUXV, AUXI, WDB, XN, XREC, ACC);
    k_cos      <<<dim3(NB),            dim3(256), 0, stream>>>(TKI, WDB, ACC);
    k_final    <<<dim3(1),             dim3(1),   0, stream>>>(ACC, scal);
}

// Round 10
// 1024.430 us; speedup vs baseline: 1.4793x; 1.0651x over previous
//
#include <hip/hip_runtime.h>

// TopK-SAE forward, MI355X.
// R9 change: k_select __launch_bounds__(256,4) -> (256,2). R9 profile showed
// VGPR_Count=64 + WRITE_SIZE=348MB/dispatch = the d[12] register array was
// SPILLED to scratch (algorithm writes only ~5MB). (256,2) caps VGPR at 256,
// d[] (48 VGPR) stays resident.
// R4: k_cos = 32x32 Gram via MFMA (350us -> off top-5, verified R9).
// R3: k_select register-bisection (457us histogram version retired).

typedef unsigned int u32;
typedef unsigned short u16;
typedef unsigned long long u64;
using short8 = __attribute__((ext_vector_type(8))) short;
using f32x4  = __attribute__((ext_vector_type(4))) float;
using u16x2  = __attribute__((ext_vector_type(2))) unsigned short;

#define NB    2048
#define DIM   768
#define DICT  24576
#define TK    32
#define TKA   256
#define ENC_K   48
#define ENC_CAP 128
#define TIE_CAP 512

#if defined(__has_builtin)
#if __has_builtin(__builtin_elementwise_sub_sat) && __has_builtin(__builtin_elementwise_min)
#define USE_PK 1
#endif
#endif

__device__ __forceinline__ u16 f2bf(float f) {
    u32 u = __float_as_uint(f);
    u32 r = (u + 0x7FFFu + ((u >> 16) & 1u)) >> 16;
    return (u16)r;
}
__device__ __forceinline__ float bf2f(u16 b) { return __uint_as_float(((u32)b) << 16); }

__device__ __forceinline__ float waveSum(float v) {
    #pragma unroll
    for (int o = 32; o; o >>= 1) v += __shfl_xor(v, o);
    return v;
}
__device__ __forceinline__ float blockSum(float v, float* red) {
    __syncthreads();
    v = waveSum(v);
    if ((threadIdx.x & 63) == 0) red[threadIdx.x >> 6] = v;
    __syncthreads();
    return red[0] + red[1] + red[2] + red[3];
}
__device__ __forceinline__ int blockSumI(int v, int* red) {
    __syncthreads();
    #pragma unroll
    for (int o = 32; o; o >>= 1) v += __shfl_xor(v, o);
    if ((threadIdx.x & 63) == 0) red[threadIdx.x >> 6] = v;
    __syncthreads();
    return red[0] + red[1] + red[2] + red[3];
}

// ---------------------------------------------------------------- init
__global__ __launch_bounds__(256) void k_init(double* acc8, u32* deadw,
                                              const int* __restrict__ nba, float* eb) {
    int t = blockIdx.x * 256 + threadIdx.x;
    if (t < 8) acc8[t] = 0.0;
    if (t < DICT / 32) {
        u32 w = 0;
        const int* p = nba + t * 32;
        #pragma unroll
        for (int b = 0; b < 32; b++) if (p[b] >= 5) w |= (1u << b);
        deadw[t] = w;
    }
    if (t < DICT) eb[t] = 0.f;
}

// ---------------------------------------------------------------- normalize
__global__ __launch_bounds__(256) void k_norm(const float* __restrict__ x,
                                              float* __restrict__ xn, u16* __restrict__ xnb,
                                              float* __restrict__ mean, float* __restrict__ sd) {
    __shared__ float red[4];
    int r = blockIdx.x, t = threadIdx.x;
    const float* xr = x + (size_t)r * DIM;
    float v0 = xr[t], v1 = xr[t + 256], v2 = xr[t + 512];
    float s = blockSum(v0 + v1 + v2, red);
    float mu = s * (1.0f / 768.0f);
    float c0 = v0 - mu, c1 = v1 - mu, c2 = v2 - mu;
    float ss = blockSum(c0 * c0 + c1 * c1 + c2 * c2, red);
    float sdv = sqrtf(ss / 767.0f);        // torch-style unbiased std (ddof=1)
    float inv = 1.0f / (sdv + 1e-5f);
    float n0 = c0 * inv, n1 = c1 * inv, n2 = c2 * inv;
    float* xo = xn + (size_t)r * DIM;
    xo[t] = n0; xo[t + 256] = n1; xo[t + 512] = n2;
    u16* xb = xnb + (size_t)r * DIM;
    xb[t] = f2bf(n0); xb[t + 256] = f2bf(n1); xb[t + 512] = f2bf(n2);
    if (t == 0) { mean[r] = mu; sd[r] = sdv; }
}

// ---------------------------------------------------------------- W_enc transpose (+bf16)
__global__ __launch_bounds__(256) void k_transpose(const float* __restrict__ We,
                                                   float* __restrict__ WeT, u16* __restrict__ WeTb) {
    __shared__ float tile[32][33];
    int kt = blockIdx.x * 32, nt = blockIdx.y * 32;
    int tx = threadIdx.x & 31, ty = threadIdx.x >> 5;   // 32 x 8
    #pragma unroll
    for (int q = 0; q < 4; q++) {
        int row = ty + q * 8;
        tile[row][tx] = We[(size_t)(kt + row) * DICT + nt + tx];
    }
    __syncthreads();
    #pragma unroll
    for (int q = 0; q < 4; q++) {
        int row = ty + q * 8;
        float v = tile[tx][row];                         // We[kt+tx][nt+row]
        size_t o = (size_t)(nt + row) * DIM + kt + tx;
        WeT[o] = v;
        WeTb[o] = f2bf(v);
    }
}

// ---------------------------------------------------------------- W_dec -> bf16
__global__ __launch_bounds__(256) void k_castdec(const float* __restrict__ Wd, u16* __restrict__ Wdb) {
    const size_t n4 = (size_t)DICT * DIM / 4;
    for (size_t i = (size_t)blockIdx.x * 256 + threadIdx.x; i < n4; i += (size_t)gridDim.x * 256) {
        float4 v = ((const float4*)Wd)[i];
        ((ushort4*)Wdb)[i] = make_ushort4(f2bf(v.x), f2bf(v.y), f2bf(v.z), f2bf(v.w));
    }
}

// ---------------------------------------------------------------- enc bias = b_dec @ W_enc
__global__ __launch_bounds__(256) void k_encbias(const float* __restrict__ bdec,
                                                 const float* __restrict__ We, float* __restrict__ eb) {
    int c = blockIdx.x * 256 + threadIdx.x;
    int k0 = blockIdx.y * 96;
    float s = 0.f;
    for (int k = k0; k < k0 + 96; k++) s += bdec[k] * We[(size_t)k * DICT + c];
    if (s != 0.f) atomicAdd(&eb[c], s);
}

// ---------------------------------------------------------------- bf16 MFMA GEMM (m97 structure)
// acts_approx = relu(xn @ W_enc - eb), stored bf16
__global__ __launch_bounds__(256) void k_gemm(const u16* __restrict__ A,   // xn bf16 [NB][DIM]
                                              const u16* __restrict__ B,   // WencT bf16 [DICT][DIM]
                                              const float* __restrict__ eb,
                                              u16* __restrict__ C) {
    __shared__ __align__(16) u16 As[128 * 32];
    __shared__ __align__(16) u16 Bs[128 * 32];
    const int K = DIM;
    int tid = threadIdx.x, lane = tid & 63, wave = tid >> 6;
    int m0 = blockIdx.y * 128, n0 = blockIdx.x * 128;
    int wm = (wave >> 1) * 64, wn = (wave & 1) * 64;
    int lrow = lane >> 2, lkq = (lane & 3) * 8;

    const u16* gA = A + (size_t)(m0 + wave * 32 + lrow) * K + lkq;
    const u16* gB = B + (size_t)(n0 + wave * 32 + lrow) * K + lkq;
    u16* lA0 = &As[(wave * 32) * 32];
    u16* lA1 = &As[(wave * 32 + 16) * 32];
    u16* lB0 = &Bs[(wave * 32) * 32];
    u16* lB1 = &Bs[(wave * 32 + 16) * 32];

    f32x4 acc[4][4];
    #pragma unroll
    for (int m = 0; m < 4; m++)
        #pragma unroll
        for (int n = 0; n < 4; n++)
            #pragma unroll
            for (int q = 0; q < 4; q++) acc[m][n][q] = 0.f;

    int fr = lane & 15, fk = (lane >> 4) * 8;
    for (int kt = 0; kt < K; kt += 32) {
        __builtin_amdgcn_global_load_lds((const __attribute__((address_space(1))) void*)(gA + kt),
                                         (__attribute__((address_space(3))) void*)lA0, 16, 0, 0);
        __builtin_amdgcn_global_load_lds((const __attribute__((address_space(1))) void*)(gA + (size_t)16 * K + kt),
                                         (__attribute__((address_space(3))) void*)lA1, 16, 0, 0);
        __builtin_amdgcn_global_load_lds((const __attribute__((address_space(1))) void*)(gB + kt),
                                         (__attribute__((address_space(3))) void*)lB0, 16, 0, 0);
        __builtin_amdgcn_global_load_lds((const __attribute__((address_space(1))) void*)(gB + (size_t)16 * K + kt),
                                         (__attribute__((address_space(3))) void*)lB1, 16, 0, 0);
        __syncthreads();
        short8 af[4], bfr[4];
        #pragma unroll
        for (int m = 0; m < 4; m++) af[m] = *(const short8*)&As[(wm + m * 16 + fr) * 32 + fk];
        #pragma unroll
        for (int n = 0; n < 4; n++) bfr[n] = *(const short8*)&Bs[(wn + n * 16 + fr) * 32 + fk];
        #pragma unroll
        for (int m = 0; m < 4; m++)
            #pragma unroll
            for (int n = 0; n < 4; n++)
                acc[m][n] = __builtin_amdgcn_mfma_f32_16x16x32_bf16(af[m], bfr[n], acc[m][n], 0, 0, 0);
        __syncthreads();
    }

    int fg = lane >> 4;
    #pragma unroll
    for (int m = 0; m < 4; m++) {
        #pragma unroll
        for (int n = 0; n < 4; n++) {
            int gcol = n0 + wn + n * 16 + fr;
            float ebv = eb[gcol];
            #pragma unroll
            for (int q = 0; q < 4; q++) {
                int grow = m0 + wm + m * 16 + fg * 4 + q;   // C/D layout (m89)
                float v = acc[m][n][q] - ebv;
                C[(size_t)grow * DICT + gcol] = f2bf(v > 0.f ? v : 0.f);
            }
        }
    }
}

// ---------------------------------------------------------------- per-row selection
// Register-resident bisection select. Row (24576 bf16) lives in 12 uint4/thread
// (48 VGPRs). launch_bounds min-waves=2 -> VGPR cap 256 -> NO SPILL (R9: the
// (256,4) bound forced 64 VGPRs and spilled d[] to scratch, 348MB writes).
__global__ __launch_bounds__(256, 2) void k_select(const u16* __restrict__ acts,
                                                   const u32* __restrict__ deadw,
                                                   u16* __restrict__ enci, int* __restrict__ encc,
                                                   float* __restrict__ auxv, int* __restrict__ auxi) {
    __shared__ u32 sdead[DICT / 32];      // 3KB
    __shared__ int red[4];
    __shared__ u32 tlist[TIE_CAP];        // 2KB
    __shared__ u32 scnt[2];               // 0: definite count, 1: tie count
    const int r = blockIdx.x, t = threadIdx.x;

    uint4 d[12];
    {
        const uint4* rowp = (const uint4*)(acts + (size_t)r * DICT);
        #pragma unroll
        for (int j = 0; j < 12; j++) d[j] = rowp[t + 256 * j];
    }
    for (int i = t; i < DICT / 32; i += 256) sdead[i] = deadw[i];

    auto cnt96 = [&](u32 T2) -> int {
#ifdef USE_PK
        unsigned short tm1s = (unsigned short)(T2 - 1u);
        u16x2 tm1 = { tm1s, tm1s };
        u16x2 one = { 1, 1 };
        u16x2 acc = { 0, 0 };
        #pragma unroll
        for (int j = 0; j < 12; j++) {
            acc = acc + __builtin_elementwise_min(
                __builtin_elementwise_sub_sat(__builtin_bit_cast(u16x2, d[j].x), tm1), one);
            acc = acc + __builtin_elementwise_min(
                __builtin_elementwise_sub_sat(__builtin_bit_cast(u16x2, d[j].y), tm1), one);
            acc = acc + __builtin_elementwise_min(
                __builtin_elementwise_sub_sat(__builtin_bit_cast(u16x2, d[j].z), tm1), one);
            acc = acc + __builtin_elementwise_min(
                __builtin_elementwise_sub_sat(__builtin_bit_cast(u16x2, d[j].w), tm1), one);
        }
        return (int)acc.x + (int)acc.y;
#else
        int c = 0;
        #pragma unroll
        for (int j = 0; j < 12; j++) {
            u32 w;
            w = d[j].x; c += (int)((w & 0xffffu) >= T2) + (int)((w >> 16) >= T2);
            w = d[j].y; c += (int)((w & 0xffffu) >= T2) + (int)((w >> 16) >= T2);
            w = d[j].z; c += (int)((w & 0xffffu) >= T2) + (int)((w >> 16) >= T2);
            w = d[j].w; c += (int)((w & 0xffffu) >= T2) + (int)((w >> 16) >= T2);
        }
        return c;
#endif
    };

    // ----------------- encoder: threshold at rank ENC_K -----------------
    u32 T = 0;
    for (int bit = 14; bit >= 0; --bit) {
        u32 T2 = T | (1u << bit);
        if (blockSumI(cnt96(T2), red) >= ENC_K) T = T2;   // uniform decision
    }

    if (t == 0) { scnt[0] = 0; scnt[1] = 0; }
    __syncthreads();
    #pragma unroll
    for (int j = 0; j < 12; j++) {
        u32 base = (u32)(t + 256 * j) * 8u;
        #pragma unroll
        for (int q = 0; q < 4; q++) {
            u32 w = q == 0 ? d[j].x : q == 1 ? d[j].y : q == 2 ? d[j].z : d[j].w;
            u32 vlo = w & 0xffffu, vhi = w >> 16;
            u32 ilo = base + 2u * q, ihi = ilo + 1u;
            if (vlo > T) { u32 p = atomicAdd(&scnt[0], 1u); enci[r * ENC_CAP + p] = (u16)ilo; }
            else if (vlo == T && T != 0) { u32 p = atomicAdd(&scnt[1], 1u); if (p < TIE_CAP) tlist[p] = ilo; }
            if (vhi > T) { u32 p = atomicAdd(&scnt[0], 1u); enci[r * ENC_CAP + p] = (u16)ihi; }
            else if (vhi == T && T != 0) { u32 p = atomicAdd(&scnt[1], 1u); if (p < TIE_CAP) tlist[p] = ihi; }
        }
    }
    __syncthreads();
    {
        u32 chi  = scnt[0];                               // < ENC_K by construction
        u32 avail = scnt[1]; if (avail > TIE_CAP) avail = TIE_CAP;
        u32 take = (u32)ENC_CAP - chi; if (take > avail) take = avail;
        for (u32 i2 = t; i2 < take; i2 += 256) enci[r * ENC_CAP + chi + i2] = (u16)tlist[i2];
        if (t == 0) encc[r] = (int)(chi + take);
    }
    __syncthreads();   // tlist reads done before aux reuse

    // ----------------- aux: mask registers to dead-only, rank TKA -----------------
    #pragma unroll
    for (int j = 0; j < 12; j++) {
        u32 g = (u32)(t + 256 * j);
        u32 m8 = (sdead[g >> 2] >> ((g & 3u) * 8u)) & 0xffu;
        d[j].x &= (((m8 >> 0) & 1u) * 0xffffu) | (((m8 >> 1) & 1u) * 0xffff0000u);
        d[j].y &= (((m8 >> 2) & 1u) * 0xffffu) | (((m8 >> 3) & 1u) * 0xffff0000u);
        d[j].z &= (((m8 >> 4) & 1u) * 0xffffu) | (((m8 >> 5) & 1u) * 0xffff0000u);
        d[j].w &= (((m8 >> 6) & 1u) * 0xffffu) | (((m8 >> 7) & 1u) * 0xffff0000u);
    }

    u32 Ta = 0;
    for (int bit = 14; bit >= 0; --bit) {
        u32 T2 = Ta | (1u << bit);
        if (blockSumI(cnt96(T2), red) >= TKA) Ta = T2;
    }

    if (t == 0) { scnt[0] = 0; scnt[1] = 0; }
    __syncthreads();
    #pragma unroll
    for (int j = 0; j < 12; j++) {
        u32 base = (u32)(t + 256 * j) * 8u;
        #pragma unroll
        for (int q = 0; q < 4; q++) {
            u32 w = q == 0 ? d[j].x : q == 1 ? d[j].y : q == 2 ? d[j].z : d[j].w;
            u32 vlo = w & 0xffffu, vhi = w >> 16;
            u32 ilo = base + 2u * q, ihi = ilo + 1u;
            if (vlo > Ta) { u32 p = atomicAdd(&scnt[0], 1u); auxi[r * TKA + p] = (int)ilo; auxv[r * TKA + p] = bf2f((u16)vlo); }
            else if (vlo == Ta && Ta != 0) { u32 p = atomicAdd(&scnt[1], 1u); if (p < TIE_CAP) tlist[p] = ilo; }
            if (vhi > Ta) { u32 p = atomicAdd(&scnt[0], 1u); auxi[r * TKA + p] = (int)ihi; auxv[r * TKA + p] = bf2f((u16)vhi); }
            else if (vhi == Ta && Ta != 0) { u32 p = atomicAdd(&scnt[1], 1u); if (p < TIE_CAP) tlist[p] = ihi; }
        }
    }
    __syncthreads();
    {
        u32 chia = scnt[0];                               // < TKA by construction
        u32 avail = (Ta != 0) ? scnt[1] : 0u; if (avail > TIE_CAP) avail = TIE_CAP;
        u32 need = (u32)TKA - chia;
        float tv = bf2f((u16)Ta);
        for (u32 i2 = t; i2 < need; i2 += 256) {
            if (i2 < avail) { auxi[r * TKA + chia + i2] = (int)tlist[i2]; auxv[r * TKA + chia + i2] = tv; }
            else            { auxi[r * TKA + chia + i2] = 0;              auxv[r * TKA + chia + i2] = 0.f; }
        }
    }
}

// ---------------------------------------------------------------- exact recompute of enc candidates + top-32
__global__ __launch_bounds__(256) void k_recompute(const float* __restrict__ xn, const float* __restrict__ WeT,
                                                   const float* __restrict__ eb,
                                                   const u16* __restrict__ enci, const int* __restrict__ encc,
                                                   float* __restrict__ tkv, int* __restrict__ tki, int* __restrict__ tkc) {
    __shared__ float sxn[DIM];
    __shared__ float cval[ENC_CAP];
    __shared__ u16 cidx[ENC_CAP];
    int r = blockIdx.x, tid = threadIdx.x, lane = tid & 63, wave = tid >> 6;
    for (int i = tid; i < DIM; i += 256) sxn[i] = xn[(size_t)r * DIM + i];
    int n = encc[r]; if (n > ENC_CAP) n = ENC_CAP; if (n < 0) n = 0;
    if (tid < ENC_CAP) cidx[tid] = (tid < n) ? enci[r * ENC_CAP + tid] : (u16)0;
    __syncthreads();
    for (int c = wave; c < n; c += 4) {
        int col = cidx[c];
        const float* wp = WeT + (size_t)col * DIM;
        double acc = 0.0;                       // f64: minimize our side of fp32 tie-noise
        #pragma unroll
        for (int j = 0; j < 12; j++) acc += (double)sxn[lane + j * 64] * (double)wp[lane + j * 64];
        #pragma unroll
        for (int o = 32; o; o >>= 1) acc += __shfl_xor(acc, o);
        if (lane == 0) { double v = acc - (double)eb[col]; cval[c] = (v > 0.0) ? (float)v : 0.f; }
    }
    __syncthreads();
    if (wave == 0) {
        u64 ka = 0, kb = 0;
        if (lane < n)      ka = (((u64)__float_as_uint(cval[lane]))      << 16) | (u64)(0xFFFFu - (u32)cidx[lane]);
        if (lane + 64 < n) kb = (((u64)__float_as_uint(cval[lane + 64])) << 16) | (u64)(0xFFFFu - (u32)cidx[lane + 64]);
        int written = 0;
        for (int it = 0; it < TK; it++) {
            u64 m = ka > kb ? ka : kb;
            #pragma unroll
            for (int o = 32; o; o >>= 1) { u64 x = __shfl_xor(m, o); if (x > m) m = x; }
            if (m == 0) break;
            if (ka == m) ka = 0; else if (kb == m) kb = 0;
            if (lane == 0) {
                tkv[r * TK + it] = __uint_as_float((u32)(m >> 16));
                tki[r * TK + it] = (int)(0xFFFFu - (u32)(m & 0xFFFFu));
            }
            written++;
        }
        if (lane == 0) {
            tkc[r] = written;
            for (int it = written; it < TK; it++) { tkv[r * TK + it] = 0.f; tki[r * TK + it] = 0; }
        }
    }
}

// ---------------------------------------------------------------- dense zero + sparse scatter
__global__ __launch_bounds__(256) void k_zero(float4* __restrict__ p, size_t n4) {
    for (size_t i = (size_t)blockIdx.x * 256 + threadIdx.x; i < n4; i += (size_t)gridDim.x * 256)
        p[i] = make_float4(0.f, 0.f, 0.f, 0.f);
}
__global__ __launch_bounds__(256) void k_scatter(const float* __restrict__ tkv, const int* __restrict__ tki,
                                                 const int* __restrict__ tkc, float* __restrict__ acts_out) {
    int g = blockIdx.x * 256 + threadIdx.x;
    int r = g >> 5, j = g & 31;
    if (j < tkc[r]) acts_out[(size_t)r * DICT + tki[g]] = tkv[g];
}

// ---------------------------------------------------------------- decode + l2/l1/l0 + sae_out
__global__ __launch_bounds__(256) void k_decode(const float* __restrict__ tkv, const int* __restrict__ tki,
                                                const int* __restrict__ tkc,
                                                const float* __restrict__ Wdec, const float* __restrict__ bdec,
                                                const float* __restrict__ xn, const float* __restrict__ mean,
                                                const float* __restrict__ sd,
                                                float* __restrict__ xrec, float* __restrict__ sae,
                                                double* __restrict__ acc8) {
    __shared__ float sv[TK]; __shared__ int si[TK]; __shared__ float red[4];
    int r = blockIdx.x, t = threadIdx.x;
    int cnt = tkc[r];
    if (t < TK) { sv[t] = (t < cnt) ? tkv[r * TK + t] : 0.f; si[t] = (t < cnt) ? tki[r * TK + t] : 0; }
    __syncthreads();
    float a0 = 0, a1 = 0, a2 = 0;
    #pragma unroll 4
    for (int j = 0; j < TK; j++) {
        float v = sv[j]; const float* wp = Wdec + (size_t)si[j] * DIM;
        a0 = fmaf(v, wp[t], a0); a1 = fmaf(v, wp[t + 256], a1); a2 = fmaf(v, wp[t + 512], a2);
    }
    a0 += bdec[t]; a1 += bdec[t + 256]; a2 += bdec[t + 512];
    size_t ro = (size_t)r * DIM;
    xrec[ro + t] = a0; xrec[ro + t + 256] = a1; xrec[ro + t + 512] = a2;
    float mu = mean[r], sdv = sd[r];
    sae[ro + t] = a0 * sdv + mu; sae[ro + t + 256] = a1 * sdv + mu; sae[ro + t + 512] = a2 * sdv + mu;
    float x0 = xn[ro + t], x1 = xn[ro + t + 256], x2 = xn[ro + t + 512];
    float d0 = a0 - x0, d1 = a1 - x1, d2 = a2 - x2;
    float l2p = blockSum(d0 * d0 + d1 * d1 + d2 * d2, red);
    float l1p = blockSum((t < TK) ? sv[t] : 0.f, red);
    float l0p = blockSum((t < TK && sv[t] > 0.f) ? 1.f : 0.f, red);
    if (t == 0) {
        atomicAdd(&acc8[0], (double)l2p);
        atomicAdd(&acc8[1], (double)l1p);
        atomicAdd(&acc8[2], (double)l0p);
    }
}

// ---------------------------------------------------------------- aux loss
__global__ __launch_bounds__(256) void k_aux(const float* __restrict__ auxv, const int* __restrict__ auxi,
                                             const u16* __restrict__ Wdb,
                                             const float* __restrict__ xn, const float* __restrict__ xrec,
                                             double* __restrict__ acc8) {
    __shared__ float sv[TKA]; __shared__ int si[TKA]; __shared__ float red[4];
    int r = blockIdx.x, t = threadIdx.x;
    sv[t] = auxv[r * TKA + t]; si[t] = auxi[r * TKA + t];
    __syncthreads();
    float a0 = 0, a1 = 0, a2 = 0;
    #pragma unroll 4
    for (int j = 0; j < TKA; j++) {
        float v = sv[j]; const u16* wp = Wdb + (size_t)si[j] * DIM;
        a0 = fmaf(v, bf2f(wp[t]), a0); a1 = fmaf(v, bf2f(wp[t + 256]), a1); a2 = fmaf(v, bf2f(wp[t + 512]), a2);
    }
    size_t ro = (size_t)r * DIM;
    float r0 = xn[ro + t] - xrec[ro + t];
    float r1 = xn[ro + t + 256] - xrec[ro + t + 256];
    float r2 = xn[ro + t + 512] - xrec[ro + t + 512];
    float e0 = a0 - r0, e1 = a1 - r1, e2 = a2 - r2;
    float s = blockSum(e0 * e0 + e1 * e1 + e2 * e2, red);
    if (t == 0) atomicAdd(&acc8[3], (double)s);
}

// ---------------------------------------------------------------- cosine penalty (MFMA Gram matrix)
// S = D * D^T for the 32 selected decoder rows (bf16, unit-norm). Full off-diag
// |S| sum (both triangles) -> k_final divides by NB*TK*(TK-1) with NO x2.
#define CPAD 8   // +8 bf16 -> row stride 1552B -> bank step 4 -> 2-way (free)
__global__ __launch_bounds__(256) void k_cos(const int* __restrict__ tki, const u16* __restrict__ Wdb,
                                             double* __restrict__ acc8) {
    __shared__ __align__(16) u16 sdec[TK][DIM + CPAD];   // ~48.5KB
    __shared__ int si[TK];
    __shared__ float red[4];
    int r = blockIdx.x, t = threadIdx.x, lane = t & 63, wave = t >> 6;
    if (t < TK) si[t] = tki[r * TK + t];
    __syncthreads();
    for (int idx = t; idx < TK * (DIM / 8); idx += 256) {
        int row = idx / (DIM / 8), c8 = idx - row * (DIM / 8);
        *(uint4*)&sdec[row][c8 * 8] = ((const uint4*)(Wdb + (size_t)si[row] * DIM))[c8];
    }
    __syncthreads();
    // wave quadrant: rows rbase..rbase+15, cols cbase..cbase+15
    int rbase = (wave >> 1) * 16, cbase = (wave & 1) * 16;
    int fr = lane & 15, fk = (lane >> 4) * 8;
    f32x4 acc = {0.f, 0.f, 0.f, 0.f};
    #pragma unroll 4
    for (int k0 = 0; k0 < DIM; k0 += 32) {
        short8 a = *(const short8*)&sdec[rbase + fr][k0 + fk];   // A row frag
        short8 b = *(const short8*)&sdec[cbase + fr][k0 + fk];   // B col frag (B=D^T)
        acc = __builtin_amdgcn_mfma_f32_16x16x32_bf16(a, b, acc, 0, 0, 0);
    }
    // C/D layout (m89): col = lane&15, row = (lane>>4)*4 + q
    float s = 0.f;
    #pragma unroll
    for (int q = 0; q < 4; q++) {
        int row = rbase + (lane >> 4) * 4 + q, col = cbase + fr;
        if (row != col) s += fabsf(acc[q]);
    }
    float tot = blockSum(s, red);
    if (t == 0) atomicAdd(&acc8[4], (double)tot);
}

// ---------------------------------------------------------------- scalars
__global__ void k_final(const double* __restrict__ acc8, float* __restrict__ outs) {
    if (threadIdx.x == 0 && blockIdx.x == 0) {
        double l2  = acc8[0] / ((double)NB * DIM);
        double l1n = acc8[1] / (double)NB;
        double l0  = acc8[2] / (double)NB;
        double l1l = 1e-4 * l1n;
        double aux = 0.03125 * (acc8[3] / ((double)NB * DIM));
        double ms  = acc8[4] / ((double)NB * TK * (TK - 1));   // full matrix summed, no x2
        double loss = l2 + l1l + aux + 0.01 * ms;
        outs[0] = (float)loss; outs[1] = (float)l2; outs[2] = (float)l1l;
        outs[3] = (float)l0;   outs[4] = (float)l1n; outs[5] = (float)aux;
        outs[6] = (float)ms;
    }
}

// ================================================================ host
extern "C" void kernel_launch(void* const* d_in, const int* in_sizes, int n_in,
                              void* d_out, int out_size, void* d_ws, size_t ws_size,
                              hipStream_t stream) {
    const float* x    = (const float*)d_in[0];
    const float* We   = (const float*)d_in[1];
    const float* Wd   = (const float*)d_in[2];
    const float* bdec = (const float*)d_in[3];
    const int*   nba  = (const int*)d_in[4];

    float* out      = (float*)d_out;
    float* sae      = out;                                  // [2048*768]
    float* acts_out = out + (size_t)NB * DIM;               // [2048*24576]
    float* scal     = out + (size_t)NB * DIM + (size_t)NB * DICT; // 7 scalars
    u16*   actsb    = (u16*)acts_out;                       // bf16 approx acts staged in output region
    // f32 W_enc^T staged in the UNUSED upper part of the acts output region:
    // read by k_recompute, wiped by k_zero afterwards.
    float* WET      = (float*)((char*)d_out + 106954752);

    char* w = (char*)d_ws;                                  // total need ~96.6MB
    float*  XN   = (float*) (w + 0);
    u16*    XNB  = (u16*)   (w + 6291456);
    float*  MEAN = (float*) (w + 9437184);
    float*  SD   = (float*) (w + 9445376);
    u16*    WETB = (u16*)   (w + 9453568);
    u16*    WDB  = (u16*)   (w + 47202304);
    float*  EB   = (float*) (w + 84951040);
    u32*    DW   = (u32*)   (w + 85049344);
    u16*    ENCI = (u16*)   (w + 85052416);   // 2048*128*2 = 524288
    int*    ENCC = (int*)   (w + 85576704);
    float*  AUXV = (float*) (w + 85584896);
    int*    AUXI = (int*)   (w + 87682048);
    float*  TKV  = (float*) (w + 89779200);
    int*    TKI  = (int*)   (w + 90041344);
    int*    TKC  = (int*)   (w + 90303488);
    float*  XREC = (float*) (w + 90311680);
    double* ACC  = (double*)(w + 96603136);

    k_init     <<<dim3(96),            dim3(256), 0, stream>>>(ACC, DW, nba, EB);
    k_norm     <<<dim3(NB),            dim3(256), 0, stream>>>(x, XN, XNB, MEAN, SD);
    k_transpose<<<dim3(24, 768),       dim3(256), 0, stream>>>(We, WET, WETB);
    k_castdec  <<<dim3(4096),          dim3(256), 0, stream>>>(Wd, WDB);
    k_encbias  <<<dim3(96, 8),         dim3(256), 0, stream>>>(bdec, We, EB);
    k_gemm     <<<dim3(DICT/128, NB/128), dim3(256), 0, stream>>>(XNB, WETB, EB, actsb);
    k_select   <<<dim3(NB),            dim3(256), 0, stream>>>(actsb, DW, ENCI, ENCC, AUXV, AUXI);
    k_recompute<<<dim3(NB),            dim3(256), 0, stream>>>(XN, WET, EB, ENCI, ENCC, TKV, TKI, TKC);
    k_zero     <<<dim3(4096),          dim3(256), 0, stream>>>((float4*)acts_out, (size_t)NB * DICT / 4);
    k_scatter  <<<dim3(NB * TK / 256), dim3(256), 0, stream>>>(TKV, TKI, TKC, acts_out);
    k_decode   <<<dim3(NB),            dim3(256), 0, stream>>>(TKV, TKI, TKC, Wd, bdec, XN, MEAN, SD, XREC, sae, ACC);
    k_aux      <<<dim3(NB),            dim3(256), 0, stream>>>(AUXV, AUXI, WDB, XN, XREC, ACC);
    k_cos      <<<dim3(NB),            dim3(256), 0, stream>>>(TKI, WDB, ACC);
    k_final    <<<dim3(1),             dim3(1),   0, stream>>>(ACC, scal);
}